// Round 6
// baseline (2466.866 us; speedup 1.0000x reference)
//
#include <hip/hip_runtime.h>

#define WAVE 64
#define CDIV(a,b) (((a)+(b)-1)/(b))

typedef float f32x16 __attribute__((ext_vector_type(16)));
typedef unsigned short u16x8 __attribute__((ext_vector_type(8)));

// ---------- bf16 helpers: hi = truncate, lo = rne(residual) ----------
__device__ __forceinline__ unsigned short f2bf_rne(float f) {
    unsigned u = __float_as_uint(f);
    unsigned r = (u + 0x7FFFu + ((u >> 16) & 1u)) >> 16;
    return (unsigned short)r;
}
__device__ __forceinline__ float bf2f(unsigned short h) {
    return __uint_as_float(((unsigned)h) << 16);
}

#define MFMA32(acc, a, b) \
    asm volatile("v_mfma_f32_32x32x16_bf16 %0, %1, %2, %0" : "+v"(acc) : "v"(a), "v"(b))

// ---------- monotonic float<->uint encoding for atomicMax on floats ----------
__device__ __forceinline__ unsigned f2mono(float f) {
    unsigned u = __float_as_uint(f);
    return (u & 0x80000000u) ? ~u : (u | 0x80000000u);
}
__device__ __forceinline__ float mono2f(unsigned u) {
    return (u & 0x80000000u) ? __uint_as_float(u & 0x7fffffffu) : __uint_as_float(~u);
}
__device__ __forceinline__ float leaky(float v) { return (v > 0.0f) ? v : 0.01f*v; }

// =========================================================================
// k_cvt: f32 [rows][K] (stride ld) -> packed bf16 hi/lo [rows][Kp], k-pad zeroed
// =========================================================================
__global__ void k_cvt(const float* __restrict__ src, long ld, int rows, int K, int Kp,
                      unsigned short* __restrict__ hi, unsigned short* __restrict__ lo)
{
    int nc4 = Kp >> 2;
    long idx = (long)blockIdx.x*blockDim.x + threadIdx.x;
    if (idx >= (long)rows * nc4) return;
    long r = idx / nc4; int k = (int)(idx % nc4) << 2;
    float4 v = {0.0f, 0.0f, 0.0f, 0.0f};
    if (k + 4 <= K) v = *(const float4*)(src + r*ld + k);
    float vv[4] = {v.x, v.y, v.z, v.w};
    ushort4 h, l;
    unsigned short hh[4], ll[4];
    #pragma unroll
    for (int i = 0; i < 4; ++i) {
        unsigned u = __float_as_uint(vv[i]);
        hh[i] = (unsigned short)(u >> 16);
        ll[i] = f2bf_rne(vv[i] - bf2f(hh[i]));
    }
    h.x = hh[0]; h.y = hh[1]; h.z = hh[2]; h.w = hh[3];
    l.x = ll[0]; l.y = ll[1]; l.z = ll[2]; l.w = ll[3];
    *(ushort4*)(hi + r*Kp + k) = h;
    *(ushort4*)(lo + r*Kp + k) = l;
}

// =========================================================================
// k_highway_cvt: out = sig(gl+b)*relu?(x2) + (1-sig)*x1, AND bf16 hi/lo of out.
// Thread per 4 cols; Kp=304 (chunk 75 = pure pad -> zeros).
// =========================================================================
__global__ void k_highway_cvt(const float* __restrict__ x1, long ld1,
                              const float* __restrict__ gl, long ldg,
                              const float* __restrict__ x2, long ld2,
                              const float* __restrict__ bias,
                              float* __restrict__ out, long ldo,
                              unsigned short* __restrict__ hi,
                              unsigned short* __restrict__ lo,
                              int rows, int relu_x2)
{
    const int nc4 = 76;                      // Kp/4
    long idx = (long)blockIdx.x*blockDim.x + threadIdx.x;
    if (idx >= (long)rows * nc4) return;
    long r = idx / nc4; int k = (int)(idx % nc4) << 2;
    if (k >= 300) {                          // pad chunk
        ushort4 z = {0,0,0,0};
        *(ushort4*)(hi + r*304 + k) = z;
        *(ushort4*)(lo + r*304 + k) = z;
        return;
    }
    float4 v1 = *(const float4*)(x1 + r*ld1 + k);
    float4 vg = *(const float4*)(gl + r*ldg + k);
    float4 v2 = *(const float4*)(x2 + r*ld2 + k);
    float4 vb = *(const float4*)(bias + k);
    float o[4];
    float a1[4] = {v1.x, v1.y, v1.z, v1.w};
    float ag[4] = {vg.x, vg.y, vg.z, vg.w};
    float a2[4] = {v2.x, v2.y, v2.z, v2.w};
    float ab[4] = {vb.x, vb.y, vb.z, vb.w};
    ushort4 h, l;
    unsigned short hh[4], ll[4];
    #pragma unroll
    for (int i = 0; i < 4; ++i) {
        float g = 1.0f / (1.0f + expf(-(ag[i] + ab[i])));
        float xv = relu_x2 ? fmaxf(a2[i], 0.0f) : a2[i];
        o[i] = g*xv + (1.0f - g)*a1[i];
        unsigned u = __float_as_uint(o[i]);
        hh[i] = (unsigned short)(u >> 16);
        ll[i] = f2bf_rne(o[i] - bf2f(hh[i]));
    }
    float4 ov = {o[0], o[1], o[2], o[3]};
    *(float4*)(out + r*ldo + k) = ov;
    h.x = hh[0]; h.y = hh[1]; h.z = hh[2]; h.w = hh[3];
    l.x = ll[0]; l.y = ll[1]; l.z = ll[2]; l.w = ll[3];
    *(ushort4*)(hi + r*304 + k) = h;
    *(ushort4*)(lo + r*304 + k) = l;
}

// =========================================================================
// k_gemm_pre: C[M,N'] = A[M,Kp] * B[N',Kp]^T on pre-split bf16 hi/lo.
// grid = (3 col-blocks [FASTEST], 782 row-blocks): the 3 col-blocks sharing
// an A row-panel dispatch back-to-back -> A re-reads hit L3/L2, HBM once.
// Block: 256 thr = 4 waves, tile 128x128. 2-deep register prefetch,
// double-buffered fragment-order LDS (conflict-free b128).
// bf16x3: AhBh + AlBh + AhBl (~fp32 accuracy).
// =========================================================================
__global__ __launch_bounds__(256, 4)
void k_gemm_pre(const unsigned short* __restrict__ Ahi, const unsigned short* __restrict__ Alo,
                const unsigned short* __restrict__ Bhi, const unsigned short* __restrict__ Blo,
                float* __restrict__ C, long ldc, int M, int N, int Kp)
{
    __shared__ __align__(16) unsigned short Ah[2][4][64][8], Al[2][4][64][8];
    __shared__ __align__(16) unsigned short Bh[2][4][64][8], Bl[2][4][64][8];

    const int tid  = threadIdx.x;
    const int lane = tid & 63;
    const int wid  = tid >> 6;              // rowtile 0..3
    const int col0 = blockIdx.x * 128;      // fastest-varying: L3 reuse of A
    const int row0 = blockIdx.y * 128;
    const int nk   = Kp >> 4;               // 19

    const bool isA = (tid < 128);
    const int  srow = isA ? tid : (tid - 128);
    const unsigned short* gh = isA ? (Ahi + (long)(row0 + srow)*Kp)
                                   : (Bhi + (long)(col0 + srow)*Kp);
    const unsigned short* gl = isA ? (Alo + (long)(row0 + srow)*Kp)
                                   : (Blo + (long)(col0 + srow)*Kp);
    const int stile = srow >> 5, slot = srow & 31;

    f32x16 acc[4];
    #pragma unroll
    for (int c = 0; c < 4; ++c) acc[c] = (f32x16)0.0f;

    u16x8 p0, p1, p2, p3, q0, q1, q2, q3;

    auto LOAD_P = [&](int t) {
        const unsigned short* ph = gh + t*16; const unsigned short* pl = gl + t*16;
        p0 = *(const u16x8*)ph; p1 = *(const u16x8*)(ph + 8);
        p2 = *(const u16x8*)pl; p3 = *(const u16x8*)(pl + 8);
    };
    auto LOAD_Q = [&](int t) {
        const unsigned short* ph = gh + t*16; const unsigned short* pl = gl + t*16;
        q0 = *(const u16x8*)ph; q1 = *(const u16x8*)(ph + 8);
        q2 = *(const u16x8*)pl; q3 = *(const u16x8*)(pl + 8);
    };

    #define WRITE_SET(a_, b_, c_, d_, buf_)                                        \
        {                                                                          \
            unsigned short* dh = isA ? &Ah[buf_][stile][slot][0]                   \
                                     : &Bh[buf_][stile][slot][0];                  \
            unsigned short* dl = isA ? &Al[buf_][stile][slot][0]                   \
                                     : &Bl[buf_][stile][slot][0];                  \
            *(u16x8*)dh = a_; *(u16x8*)(dh + 256) = b_;                            \
            *(u16x8*)dl = c_; *(u16x8*)(dl + 256) = d_;                            \
        }

    #define MFMA_STEP(buf_)                                                       \
        {                                                                          \
            u16x8 afh = *(const u16x8*)&Ah[buf_][wid][lane][0];                    \
            u16x8 afl = *(const u16x8*)&Al[buf_][wid][lane][0];                    \
            _Pragma("unroll")                                                      \
            for (int c = 0; c < 4; ++c) {                                          \
                u16x8 bfh = *(const u16x8*)&Bh[buf_][c][lane][0];                  \
                u16x8 bfl = *(const u16x8*)&Bl[buf_][c][lane][0];                  \
                MFMA32(acc[c], afh, bfh);                                          \
                MFMA32(acc[c], afl, bfh);                                          \
                MFMA32(acc[c], afh, bfl);                                          \
            }                                                                      \
        }

    // prologue: load k-steps 0,1; write 0 into buf0
    LOAD_P(0);
    LOAD_Q(1);
    WRITE_SET(p0, p1, p2, p3, 0);
    __syncthreads();

    int t = 0;
    for (;;) {
        // even step t: compute buf0; q holds t+1
        bool wr1 = (t + 1 < nk);
        if (t + 2 < nk) LOAD_P(t + 2);
        if (wr1) WRITE_SET(q0, q1, q2, q3, 1);
        MFMA_STEP(0);
        __syncthreads();
        if (!wr1) break;
        // odd step t+1: compute buf1; p holds t+2
        bool wr2 = (t + 2 < nk);
        if (t + 3 < nk) LOAD_Q(t + 3);
        if (wr2) WRITE_SET(p0, p1, p2, p3, 0);
        MFMA_STEP(1);
        __syncthreads();
        if (!wr2) break;
        t += 2;
    }
    #undef WRITE_SET
    #undef MFMA_STEP

    // epilogue: C/D layout col=lane&31, row=(reg&3)+8*(reg>>2)+4*(lane>>5)
    const int crow0 = row0 + wid*32 + 4*(lane >> 5);
    const int ccol0 = col0 + (lane & 31);
    #pragma unroll
    for (int c = 0; c < 4; ++c) {
        int col = ccol0 + c*32;
        if (col >= N) continue;
        #pragma unroll
        for (int reg = 0; reg < 16; ++reg) {
            int row = crow0 + (reg & 3) + 8*(reg >> 2);
            if (row < M) C[(long)row*ldc + col] = acc[c][reg];
        }
    }
}

// ---------- small f32 GEMM (tiny R x RH highway gate) ----------
#define GBM 64
#define GBN 64
#define GBK 16
__global__ __launch_bounds__(256)
void k_gemm(const float* __restrict__ A, long lda,
            const float* __restrict__ B, long ldb,
            float* __restrict__ C, long ldc,
            int M, int N, int K)
{
    __shared__ float As[GBK][GBM + 4];
    __shared__ float Bs[GBK][GBN + 4];
    const int tid = threadIdx.x;
    const int tx = tid & 15, ty = tid >> 4;
    const int row0 = blockIdx.y * GBM, col0 = blockIdx.x * GBN;
    float acc[4][4] = {};
    for (int kt = 0; kt < K; kt += GBK) {
        #pragma unroll
        for (int p = 0; p < 4; ++p) {
            int mn = (tid >> 4) + p * 16;
            int k  = tid & 15;
            int gk = kt + k;
            int gr = row0 + mn;
            As[k][mn] = (gr < M && gk < K) ? A[(long)gr * lda + gk] : 0.0f;
            int gc = col0 + mn;
            Bs[k][mn] = (gc < N && gk < K) ? B[(long)gc * ldb + gk] : 0.0f;
        }
        __syncthreads();
        #pragma unroll
        for (int kk = 0; kk < GBK; ++kk) {
            float a0 = As[kk][ty*4+0], a1 = As[kk][ty*4+1];
            float a2 = As[kk][ty*4+2], a3 = As[kk][ty*4+3];
            float b0 = Bs[kk][tx*4+0], b1 = Bs[kk][tx*4+1];
            float b2 = Bs[kk][tx*4+2], b3 = Bs[kk][tx*4+3];
            acc[0][0] += a0*b0; acc[0][1] += a0*b1; acc[0][2] += a0*b2; acc[0][3] += a0*b3;
            acc[1][0] += a1*b0; acc[1][1] += a1*b1; acc[1][2] += a1*b2; acc[1][3] += a1*b3;
            acc[2][0] += a2*b0; acc[2][1] += a2*b1; acc[2][2] += a2*b2; acc[2][3] += a2*b3;
            acc[3][0] += a3*b0; acc[3][1] += a3*b1; acc[3][2] += a3*b2; acc[3][3] += a3*b3;
        }
        __syncthreads();
    }
    #pragma unroll
    for (int i2 = 0; i2 < 4; ++i2)
        #pragma unroll
        for (int j2 = 0; j2 < 4; ++j2) {
            int r = row0 + ty*4 + i2, c = col0 + tx*4 + j2;
            if (r < M && c < N) C[(long)r*ldc + c] = acc[i2][j2];
        }
}

// ================= CSR build: histogram -> scan -> fill =================
__global__ void k_hist(const int* __restrict__ key, int* __restrict__ cnt, int E) {
    int e = blockIdx.x*blockDim.x + threadIdx.x;
    if (e < E) atomicAdd(&cnt[key[e]], 1);
}
__global__ void k_scan1(const int* __restrict__ in, int* __restrict__ out,
                        int* __restrict__ bsum, int n) {
    __shared__ int sh[256];
    int gid = blockIdx.x*256 + threadIdx.x;
    int v = (gid < n) ? in[gid] : 0;
    sh[threadIdx.x] = v; __syncthreads();
    for (int o = 1; o < 256; o <<= 1) {
        int t = (threadIdx.x >= o) ? sh[threadIdx.x - o] : 0;
        __syncthreads();
        sh[threadIdx.x] += t;
        __syncthreads();
    }
    if (gid < n) out[gid] = sh[threadIdx.x] - v;      // exclusive
    if (threadIdx.x == 255) bsum[blockIdx.x] = sh[255];
}
__global__ void k_scan2(int* __restrict__ bsum, int nb) {   // single block, nb <= 1024
    __shared__ int sh[1024];
    int v = (threadIdx.x < nb) ? bsum[threadIdx.x] : 0;
    sh[threadIdx.x] = v; __syncthreads();
    for (int o = 1; o < 1024; o <<= 1) {
        int t = (threadIdx.x >= o) ? sh[threadIdx.x - o] : 0;
        __syncthreads();
        sh[threadIdx.x] += t;
        __syncthreads();
    }
    if (threadIdx.x < nb) bsum[threadIdx.x] = sh[threadIdx.x] - v;  // exclusive
}
__global__ void k_scan3(int* __restrict__ out, const int* __restrict__ bsum, int n) {
    int gid = blockIdx.x*256 + threadIdx.x;
    if (gid < n) out[gid] += bsum[blockIdx.x];
}
__global__ void k_fill(const int* __restrict__ key, const int* __restrict__ rowptr,
                       int* __restrict__ cursor, int* __restrict__ perm, int E) {
    int e = blockIdx.x*blockDim.x + threadIdx.x;
    if (e >= E) return;
    int k = key[e];
    int p = rowptr[k] + atomicAdd(&cursor[k], 1);
    perm[p] = e;
}
__global__ void k_dinv_cnt(const int* __restrict__ cnt, float* __restrict__ dinv, int n) {
    int i = blockIdx.x*blockDim.x + threadIdx.x;
    if (i < n) { int c = cnt[i]; dinv[i] = (c > 0) ? rsqrtf((float)c) : 0.0f; }
}

// ---------- CSR-order pre-permutation ----------
__global__ void k_prep_gcn(const int* __restrict__ perm, const int* __restrict__ jA,
                           const int* __restrict__ iA, const float* __restrict__ dinv,
                           int* __restrict__ jp, float* __restrict__ nm, int E) {
    int p = blockIdx.x*blockDim.x + threadIdx.x;
    if (p >= E) return;
    int e = perm[p];
    int j = jA[e];
    jp[p] = j;
    nm[p] = dinv[iA[e]] * dinv[j];
}
__global__ void k_permute_i32(const int* __restrict__ src, const int* __restrict__ perm,
                              int* __restrict__ dst, int E) {
    int p = blockIdx.x*blockDim.x + threadIdx.x;
    if (p < E) dst[p] = src[perm[p]];
}
__global__ void k_permute_mod(const int* __restrict__ src, const int* __restrict__ perm,
                              int* __restrict__ dst, int E, int mod) {
    int p = blockIdx.x*blockDim.x + threadIdx.x;
    if (p < E) dst[p] = src[perm[p]] % mod;
}

// ============ gather aggregations (wave per destination node, F=300) ============
__global__ void k_gather300(const float* __restrict__ x, long ldx,
                            const int* __restrict__ jp, const float* __restrict__ nm,
                            const int* __restrict__ rowptr, const int* __restrict__ cnt,
                            float* __restrict__ out, long ldo, int n)
{
    int w = (blockIdx.x*blockDim.x + threadIdx.x) >> 6;
    int lane = threadIdx.x & 63;
    if (w >= n) return;
    int beg = rowptr[w], end = beg + cnt[w];
    const int i0 = lane, i1 = lane + 64, i2 = lane + 128;
    const bool t3 = (lane < 22);
    float2 a0 = {0,0}, a1 = {0,0}, a2 = {0,0};
    int e = beg;
    for (; e + 4 <= end; e += 4) {
        const float2* r0 = (const float2*)(x + (long)jp[e]  *ldx);
        const float2* r1 = (const float2*)(x + (long)jp[e+1]*ldx);
        const float2* r2 = (const float2*)(x + (long)jp[e+2]*ldx);
        const float2* r3 = (const float2*)(x + (long)jp[e+3]*ldx);
        float w0 = nm[e], w1 = nm[e+1], w2 = nm[e+2], w3 = nm[e+3];
        float2 v;
        v = r0[i0]; a0.x += w0*v.x; a0.y += w0*v.y;
        v = r1[i0]; a0.x += w1*v.x; a0.y += w1*v.y;
        v = r2[i0]; a0.x += w2*v.x; a0.y += w2*v.y;
        v = r3[i0]; a0.x += w3*v.x; a0.y += w3*v.y;
        v = r0[i1]; a1.x += w0*v.x; a1.y += w0*v.y;
        v = r1[i1]; a1.x += w1*v.x; a1.y += w1*v.y;
        v = r2[i1]; a1.x += w2*v.x; a1.y += w2*v.y;
        v = r3[i1]; a1.x += w3*v.x; a1.y += w3*v.y;
        if (t3) {
            v = r0[i2]; a2.x += w0*v.x; a2.y += w0*v.y;
            v = r1[i2]; a2.x += w1*v.x; a2.y += w1*v.y;
            v = r2[i2]; a2.x += w2*v.x; a2.y += w2*v.y;
            v = r3[i2]; a2.x += w3*v.x; a2.y += w3*v.y;
        }
    }
    for (; e < end; ++e) {
        const float2* r0 = (const float2*)(x + (long)jp[e]*ldx);
        float w0 = nm[e];
        float2 v;
        v = r0[i0]; a0.x += w0*v.x; a0.y += w0*v.y;
        v = r0[i1]; a1.x += w0*v.x; a1.y += w0*v.y;
        if (t3) { v = r0[i2]; a2.x += w0*v.x; a2.y += w0*v.y; }
    }
    float2* dst = (float2*)(out + (long)w*ldo);
    dst[i0] = a0; dst[i1] = a1;
    if (t3) dst[i2] = a2;
}

// GAT: fused edge score + segment softmax + weighted gather + relu (F=300)
__global__ void k_gat300(const float* __restrict__ x, long ldx,
                         const float* __restrict__ sA, const float* __restrict__ sB,
                         const float* __restrict__ rsc,
                         const int* __restrict__ jp, const int* __restrict__ relp,
                         const int* __restrict__ rowptr, const int* __restrict__ cnt,
                         float* __restrict__ out, long ldo, int n)
{
    int w = (blockIdx.x*blockDim.x + threadIdx.x) >> 6;
    int lane = threadIdx.x & 63;
    if (w >= n) return;
    int beg = rowptr[w], c = cnt[w];
    const int i0 = lane, i1 = lane + 64, i2 = lane + 128;
    const bool t3 = (lane < 22);
    float2 a0 = {0,0}, a1 = {0,0}, a2 = {0,0};
    if (c > 0) {
        float base = sA[w];
        int   jc = 0;
        float sval = -3.4e38f;
        if (lane < c) {
            jc = jp[beg + lane];
            sval = leaky(base + sB[jc] + rsc[relp[beg + lane]]);
        }
        float mx = sval;
        for (int t = 64 + lane; t < c; t += 64)
            mx = fmaxf(mx, leaky(base + sB[jp[beg+t]] + rsc[relp[beg+t]]));
        #pragma unroll
        for (int o = 32; o > 0; o >>= 1) mx = fmaxf(mx, __shfl_xor(mx, o));
        float pexp = (lane < c) ? expf(sval - mx) : 0.0f;
        float ss = pexp;
        for (int t = 64 + lane; t < c; t += 64)
            ss += expf(leaky(base + sB[jp[beg+t]] + rsc[relp[beg+t]]) - mx);
        #pragma unroll
        for (int o = 32; o > 0; o >>= 1) ss += __shfl_xor(ss, o);
        float inv = 1.0f / (ss + 1e-16f);
        int q = 0;
        int cc = (c < 64) ? c : 64;
        for (; q + 4 <= cc; q += 4) {
            float al0 = __shfl(pexp, q)   * inv;
            float al1 = __shfl(pexp, q+1) * inv;
            float al2 = __shfl(pexp, q+2) * inv;
            float al3 = __shfl(pexp, q+3) * inv;
            long  j0 = __shfl(jc, q), j1 = __shfl(jc, q+1);
            long  j2 = __shfl(jc, q+2), j3 = __shfl(jc, q+3);
            const float2* r0 = (const float2*)(x + j0*ldx);
            const float2* r1 = (const float2*)(x + j1*ldx);
            const float2* r2 = (const float2*)(x + j2*ldx);
            const float2* r3 = (const float2*)(x + j3*ldx);
            float2 v;
            v = r0[i0]; a0.x += al0*v.x; a0.y += al0*v.y;
            v = r1[i0]; a0.x += al1*v.x; a0.y += al1*v.y;
            v = r2[i0]; a0.x += al2*v.x; a0.y += al2*v.y;
            v = r3[i0]; a0.x += al3*v.x; a0.y += al3*v.y;
            v = r0[i1]; a1.x += al0*v.x; a1.y += al0*v.y;
            v = r1[i1]; a1.x += al1*v.x; a1.y += al1*v.y;
            v = r2[i1]; a1.x += al2*v.x; a1.y += al2*v.y;
            v = r3[i1]; a1.x += al3*v.x; a1.y += al3*v.y;
            if (t3) {
                v = r0[i2]; a2.x += al0*v.x; a2.y += al0*v.y;
                v = r1[i2]; a2.x += al1*v.x; a2.y += al1*v.y;
                v = r2[i2]; a2.x += al2*v.x; a2.y += al2*v.y;
                v = r3[i2]; a2.x += al3*v.x; a2.y += al3*v.y;
            }
        }
        for (; q < c; ++q) {
            float al; long j0;
            if (q < 64) { al = __shfl(pexp, q) * inv; j0 = __shfl(jc, q); }
            else {
                j0 = jp[beg + q];
                al = expf(leaky(base + sB[(int)j0] + rsc[relp[beg+q]]) - mx) * inv;
            }
            const float2* r0 = (const float2*)(x + j0*ldx);
            float2 v;
            v = r0[i0]; a0.x += al*v.x; a0.y += al*v.y;
            v = r0[i1]; a1.x += al*v.x; a1.y += al*v.y;
            if (t3) { v = r0[i2]; a2.x += al*v.x; a2.y += al*v.y; }
        }
    }
    float2* dst = (float2*)(out + (long)w*ldo);
    a0.x = fmaxf(a0.x, 0.0f); a0.y = fmaxf(a0.y, 0.0f);
    a1.x = fmaxf(a1.x, 0.0f); a1.y = fmaxf(a1.y, 0.0f);
    dst[i0] = a0; dst[i1] = a1;
    if (t3) { a2.x = fmaxf(a2.x, 0.0f); a2.y = fmaxf(a2.y, 0.0f); dst[i2] = a2; }
}

// r2e: fused score = leaky(snode[w] + srel[relp]) + softmax + gather of xr (F=100)
__global__ void k_gather_rel100(const float* __restrict__ xr,
                                const float* __restrict__ snode,
                                const float* __restrict__ srel,
                                const int* __restrict__ relp,
                                const int* __restrict__ rowptr, const int* __restrict__ cnt,
                                float* __restrict__ out, long ldo, int n)
{
    int w = (blockIdx.x*blockDim.x + threadIdx.x) >> 6;
    int lane = threadIdx.x & 63;
    if (w >= n) return;
    int beg = rowptr[w], c = cnt[w];
    const bool t0 = (lane < 50);
    float2 a0 = {0,0};
    if (c > 0) {
        float base = snode[w];
        int   rc = 0;
        float sval = -3.4e38f;
        if (lane < c) {
            rc = relp[beg + lane];
            sval = leaky(base + srel[rc]);
        }
        float mx = sval;
        for (int t = 64 + lane; t < c; t += 64)
            mx = fmaxf(mx, leaky(base + srel[relp[beg+t]]));
        #pragma unroll
        for (int o = 32; o > 0; o >>= 1) mx = fmaxf(mx, __shfl_xor(mx, o));
        float pexp = (lane < c) ? expf(sval - mx) : 0.0f;
        float ss = pexp;
        for (int t = 64 + lane; t < c; t += 64)
            ss += expf(leaky(base + srel[relp[beg+t]]) - mx);
        #pragma unroll
        for (int o = 32; o > 0; o >>= 1) ss += __shfl_xor(ss, o);
        float inv = 1.0f / (ss + 1e-16f);
        int q = 0;
        int cc = (c < 64) ? c : 64;
        for (; q + 4 <= cc; q += 4) {
            float al0 = __shfl(pexp, q)   * inv;
            float al1 = __shfl(pexp, q+1) * inv;
            float al2 = __shfl(pexp, q+2) * inv;
            float al3 = __shfl(pexp, q+3) * inv;
            long r0i = __shfl(rc, q), r1i = __shfl(rc, q+1);
            long r2i = __shfl(rc, q+2), r3i = __shfl(rc, q+3);
            if (t0) {
                float2 v;
                v = ((const float2*)(xr + r0i*100))[lane]; a0.x += al0*v.x; a0.y += al0*v.y;
                v = ((const float2*)(xr + r1i*100))[lane]; a0.x += al1*v.x; a0.y += al1*v.y;
                v = ((const float2*)(xr + r2i*100))[lane]; a0.x += al2*v.x; a0.y += al2*v.y;
                v = ((const float2*)(xr + r3i*100))[lane]; a0.x += al3*v.x; a0.y += al3*v.y;
            }
        }
        for (; q < c; ++q) {
            float al; long r0i;
            if (q < 64) { al = __shfl(pexp, q) * inv; r0i = __shfl(rc, q); }
            else {
                r0i = relp[beg + q];
                al = expf(leaky(base + srel[(int)r0i]) - mx) * inv;
            }
            if (t0) {
                float2 v = ((const float2*)(xr + r0i*100))[lane];
                a0.x += al*v.x; a0.y += al*v.y;
            }
        }
    }
    if (t0) ((float2*)(out + (long)w*ldo))[lane] = a0;
}

// ---------- highway combine ----------
__global__ void k_highway(const float* __restrict__ x1, long ld1,
                          const float* __restrict__ gl, long ldg,
                          const float* __restrict__ x2, long ld2,
                          const float* __restrict__ bias,
                          float* __restrict__ out, long ldo,
                          long rows, int F, int relu_x2)
{
    long idx = (long)blockIdx.x*blockDim.x + threadIdx.x;
    if (idx >= rows * (long)F) return;
    long r = idx / F; int c = (int)(idx % F);
    float g = 1.0f / (1.0f + expf(-(gl[r*ldg+c] + bias[c])));
    float v2 = x2[r*ld2+c]; if (relu_x2) v2 = fmaxf(v2, 0.0f);
    float v1 = x1[r*ld1+c];
    out[r*ldo+c] = g*v2 + (1.0f-g)*v1;
}

// ---------- segment softmax building blocks (small l_gat path only) ----------
__global__ void k_segmax(const float* __restrict__ ev, const int* __restrict__ idx,
                         unsigned* __restrict__ m, int E) {
    int e = blockIdx.x*blockDim.x + threadIdx.x;
    if (e < E) atomicMax(&m[idx[e]], f2mono(ev[e]));
}
__global__ void k_segsumexp(const float* __restrict__ ev, const int* __restrict__ idx,
                            const unsigned* __restrict__ m, float* __restrict__ s, int E) {
    int e = blockIdx.x*blockDim.x + threadIdx.x;
    if (e < E) atomicAdd(&s[idx[e]], expf(ev[e] - mono2f(m[idx[e]])));
}
__global__ void k_lgat_vsum(const float* __restrict__ val,
                            const int* __restrict__ jj, const int* __restrict__ ii,
                            const unsigned* __restrict__ mi, const float* __restrict__ si,
                            const unsigned* __restrict__ mj, const float* __restrict__ sj,
                            float* __restrict__ vsum, int E)
{
    int e = blockIdx.x*blockDim.x + threadIdx.x;
    if (e >= E) return;
    float v = val[e];
    int i = ii[e], j = jj[e];
    float pi = expf(v - mono2f(mi[i])) / (si[i] + 1e-16f);
    float pj = expf(v - mono2f(mj[j])) / (sj[j] + 1e-16f);
    vsum[e] = pi + pj;
}
__global__ void k_edge_agg(const float* __restrict__ ev,
                           const unsigned* __restrict__ m, const float* __restrict__ s,
                           const int* __restrict__ ka, const int* __restrict__ ko,
                           const int* __restrict__ ks,
                           const float* __restrict__ x, long ldx,
                           float* __restrict__ out, long ldo,
                           int E, int F)
{
    int w = (blockIdx.x*blockDim.x + threadIdx.x) >> 6;
    int lane = threadIdx.x & 63;
    if (w >= E) return;
    int a = ka[w];
    float alpha = expf(ev[w] - mono2f(m[a])) / (s[a] + 1e-16f);
    const float4* src = (const float4*)(x + (long)ks[w]*ldx);
    float* dst = out + (long)ko[w]*ldo;
    int nf4 = F >> 2;
    for (int f = lane; f < nf4; f += WAVE) {
        float4 v = src[f];
        atomicAdd(&dst[f*4+0], alpha*v.x);
        atomicAdd(&dst[f*4+1], alpha*v.y);
        atomicAdd(&dst[f*4+2], alpha*v.z);
        atomicAdd(&dst[f*4+3], alpha*v.w);
    }
}
__global__ void k_relu2d(float* __restrict__ p, long rows, int cols, long ld) {
    long idx = (long)blockIdx.x*blockDim.x + threadIdx.x;
    if (idx >= rows*(long)cols) return;
    long r = idx / cols; int c = (int)(idx % cols);
    float v = p[r*ld+c];
    p[r*ld+c] = fmaxf(v, 0.0f);
}

// ---------- row dots ----------
__global__ void k_rowdot2(const float* __restrict__ x, long ldx, int rows, int K,
                          const float* __restrict__ a, const float* __restrict__ b,
                          float* __restrict__ oa, float* __restrict__ ob)
{
    int w = (blockIdx.x*blockDim.x + threadIdx.x) >> 6;
    int lane = threadIdx.x & 63;
    if (w >= rows) return;
    const float* xr = x + (long)w*ldx;
    float sa = 0.0f, sb = 0.0f;
    for (int k = lane; k < K; k += WAVE) {
        float v = xr[k];
        sa += v * a[k];
        if (b) sb += v * b[k];
    }
    #pragma unroll
    for (int off = 32; off > 0; off >>= 1) {
        sa += __shfl_down(sa, off);
        if (b) sb += __shfl_down(sb, off);
    }
    if (lane == 0) { oa[w] = sa; if (ob) ob[w] = sb; }
}

// ---------- relscore[r] = merge[r]·ar[0:RH] + tri[r]·ar[RH:2RH] ----------
__global__ void k_relscore(const float* __restrict__ mg, const float* __restrict__ tr,
                           const float* __restrict__ ar, float* __restrict__ out, int R, int RH)
{
    int w = (blockIdx.x*blockDim.x + threadIdx.x) >> 6;
    int lane = threadIdx.x & 63;
    if (w >= R) return;
    float s = 0.0f;
    for (int k = lane; k < RH; k += WAVE)
        s += mg[(long)w*RH+k]*ar[k] + tr[(long)w*RH+k]*ar[RH+k];
    #pragma unroll
    for (int off = 32; off > 0; off >>= 1) s += __shfl_down(s, off);
    if (lane == 0) out[w] = s;
}

extern "C" void kernel_launch(void* const* d_in, const int* in_sizes, int n_in,
                              void* d_out, int out_size, void* d_ws, size_t ws_size,
                              hipStream_t stream)
{
    const float* x_e   = (const float*)d_in[0];
    const float* mval  = (const float*)d_in[1];
    const float* tval  = (const float*)d_in[2];
    const float* g1w   = (const float*)d_in[3];
    const float* h1w   = (const float*)d_in[4];
    const float* h1b   = (const float*)d_in[5];
    const float* g2w   = (const float*)d_in[6];
    const float* h2w   = (const float*)d_in[7];
    const float* h2b   = (const float*)d_in[8];
    const float* remb1 = (const float*)d_in[9];
    const float* remb2 = (const float*)d_in[10];
    const float* hrw   = (const float*)d_in[11];
    const float* hrb   = (const float*)d_in[12];
    const float* gat_ai= (const float*)d_in[13];
    const float* gat_aj= (const float*)d_in[14];
    const float* gat_ar= (const float*)d_in[15];
    const float* g2e_ah= (const float*)d_in[16];
    const float* g2e_at= (const float*)d_in[17];
    const float* g2e_ar= (const float*)d_in[18];
    const int* edge_index     = (const int*)d_in[19];
    const int* rel            = (const int*)d_in[20];
    const int* edge_index_all = (const int*)d_in[21];
    const int* rel_all        = (const int*)d_in[22];
    const int* lg_merge       = (const int*)d_in[23];
    const int* lg_tri         = (const int*)d_in[24];

    const int F    = 300;
    const int RH   = 100;
    const int Kp   = 304;                  // padded K for bf16 arrays
    const int N    = in_sizes[0] / F;      // 100000
    const int E    = in_sizes[20];         // 400000
    const int EA   = in_sizes[22];         // 800000
    const int LGE  = in_sizes[1];          // 60000
    const int R    = in_sizes[9] / RH;     // 2000
    const long OUTC = 800;
    const int Mpad = CDIV(N, 128) * 128;   // 100096
    const int Npad = 384;                  // 3 col-blocks of 128

    const int* jA = edge_index_all;
    const int* iA = edge_index_all + EA;
    const int* hE = edge_index;
    const int* tE = edge_index + E;
    const int* jM = lg_merge;  const int* iM = lg_merge + LGE;
    const int* jT = lg_tri;    const int* iT = lg_tri  + LGE;

    float* ws = (float*)d_ws;
    size_t off = 0;
    auto alloc = [&](size_t n) { float* p = ws + off; off += (n + 3) & ~(size_t)3; return p; };
    float*    Ascr = alloc((size_t)N*F);                       // GEMM output scratch f32
    unsigned short* Axh = (unsigned short*)alloc((size_t)Mpad*Kp/2);  // A bf16 hi
    unsigned short* Axl = (unsigned short*)alloc((size_t)Mpad*Kp/2);  // A bf16 lo
    unsigned short* Wh[4]; unsigned short* Wl[4];
    for (int i = 0; i < 4; ++i) {
        Wh[i] = (unsigned short*)alloc((size_t)Npad*Kp/2);
        Wl[i] = (unsigned short*)alloc((size_t)Npad*Kp/2);
    }
    float*    dinv = alloc(N);
    float*    sA_  = alloc(N);
    float*    sB_  = alloc(N);
    float*    mrg  = alloc((size_t)R*RH);
    float*    tri  = alloc((size_t)R*RH);
    float*    xr   = alloc((size_t)R*RH);
    float*    xrg  = alloc((size_t)R*RH);
    unsigned* lmi  = (unsigned*)alloc(R);  float* lsi = alloc(R);
    unsigned* lmj  = (unsigned*)alloc(R);  float* lsj = alloc(R);
    unsigned* lm2  = (unsigned*)alloc(R);  float* ls2 = alloc(R);
    float*    vsum = alloc(LGE);
    float*    rsc  = alloc(R);
    float*    srel = alloc(R);
    int*   bsum    = (int*)alloc(1024);
    int*   cursor  = (int*)alloc(N);
    int*   rowptrA = (int*)alloc(N); int* cntA = (int*)alloc(N); int* permA = (int*)alloc(EA);
    int*   rowptrH = (int*)alloc(N); int* cntH = (int*)alloc(N); int* permH = (int*)alloc(E);
    int*   rowptrT = (int*)alloc(N); int* cntT = (int*)alloc(N); int* permT = (int*)alloc(E);
    int*   jpA     = (int*)alloc(EA);
    float* nmA     = alloc(EA);
    int*   relpA   = (int*)alloc(EA);
    int*   relpH   = (int*)alloc(E);
    int*   relpT   = (int*)alloc(E);

    float* out = (float*)d_out;              // [N, 800]

    const long NF = (long)N * F;
    const int  nb = CDIV(N, 256);
    dim3 gemmGrid(3, CDIV(N, 128));          // col fastest -> L3 reuse of A panels
    const int gatherGrid = CDIV(N, 4);
    const int cvtBigGrid = CDIV((long)N * (Kp/4), 256);
    const int cvtWGrid   = CDIV(300 * (Kp/4), 256);
    const int hwcGrid    = CDIV((long)N * (Kp/4), 256);

    auto build_csr = [&](const int* key, int E_, int* rowptr, int* cnt, int* perm) {
        hipMemsetAsync(cnt, 0, (size_t)N*4, stream);
        k_hist<<<CDIV(E_,256),256,0,stream>>>(key, cnt, E_);
        k_scan1<<<nb,256,0,stream>>>(cnt, rowptr, bsum, N);
        k_scan2<<<1,1024,0,stream>>>(bsum, nb);
        k_scan3<<<nb,256,0,stream>>>(rowptr, bsum, N);
        hipMemsetAsync(cursor, 0, (size_t)N*4, stream);
        k_fill<<<CDIV(E_,256),256,0,stream>>>(key, rowptr, cursor, perm, E_);
    };

    // ===== zero pad rows (W rows 300..383; Ax rows N..Mpad) then converts =====
    for (int i = 0; i < 4; ++i) {
        hipMemsetAsync(Wh[i], 0, (size_t)Npad*Kp*2, stream);
        hipMemsetAsync(Wl[i], 0, (size_t)Npad*Kp*2, stream);
    }
    hipMemsetAsync(Axh + (size_t)N*Kp, 0, (size_t)(Mpad-N)*Kp*2, stream);
    hipMemsetAsync(Axl + (size_t)N*Kp, 0, (size_t)(Mpad-N)*Kp*2, stream);
    k_cvt<<<cvtWGrid,256,0,stream>>>(g1w, 300, 300, 300, Kp, Wh[0], Wl[0]);
    k_cvt<<<cvtWGrid,256,0,stream>>>(h1w, 300, 300, 300, Kp, Wh[1], Wl[1]);
    k_cvt<<<cvtWGrid,256,0,stream>>>(g2w, 300, 300, 300, Kp, Wh[2], Wl[2]);
    k_cvt<<<cvtWGrid,256,0,stream>>>(h2w, 300, 300, 300, Kp, Wh[3], Wl[3]);
    k_cvt<<<cvtBigGrid,256,0,stream>>>(x_e, 300, N, 300, Kp, Axh, Axl);

    // ===== CSRs + pre-permutes =====
    build_csr(iA, EA, rowptrA, cntA, permA);
    build_csr(hE, E,  rowptrH, cntH, permH);
    build_csr(tE, E,  rowptrT, cntT, permT);
    k_dinv_cnt<<<CDIV(N,256),256,0,stream>>>(cntA, dinv, N);
    k_prep_gcn<<<CDIV(EA,256),256,0,stream>>>(permA, jA, iA, dinv, jpA, nmA, EA);
    k_permute_mod<<<CDIV(EA,256),256,0,stream>>>(rel_all, permA, relpA, EA, R);
    k_permute_i32<<<CDIV(E,256),256,0,stream>>>(rel, permH, relpH, E);
    k_permute_i32<<<CDIV(E,256),256,0,stream>>>(rel, permT, relpT, E);

    // ===== GCN layer 1 + highway (fused with bf16 re-convert for layer 2) =====
    k_gemm_pre<<<gemmGrid,256,0,stream>>>(Axh, Axl, Wh[0], Wl[0], Ascr, F, N, F, Kp);
    k_gather300<<<gatherGrid,256,0,stream>>>(Ascr, F, jpA, nmA, rowptrA, cntA, out+300, OUTC, N);
    k_gemm_pre<<<gemmGrid,256,0,stream>>>(Axh, Axl, Wh[1], Wl[1], Ascr, F, N, F, Kp);
    k_highway_cvt<<<hwcGrid,256,0,stream>>>(x_e, F, Ascr, F, out+300, OUTC, h1b,
                                            out, OUTC, Axh, Axl, N, 1);

    // ===== GCN layer 2 + highway =====
    k_gemm_pre<<<gemmGrid,256,0,stream>>>(Axh, Axl, Wh[2], Wl[2], Ascr, F, N, F, Kp);
    k_gather300<<<gatherGrid,256,0,stream>>>(Ascr, F, jpA, nmA, rowptrA, cntA, out+300, OUTC, N);
    k_gemm_pre<<<gemmGrid,256,0,stream>>>(Axh, Axl, Wh[3], Wl[3], Ascr, F, N, F, Kp);
    k_highway<<<CDIV(NF,256),256,0,stream>>>(out, OUTC, Ascr, F, out+300, OUTC, h2b, out, OUTC, N, F, 1);

    // ===== l_gat on the two line graphs (small; atomic path) =====
    auto lgat = [&](const float* xrel, const int* jjE, const int* iiE, const float* val, float* obuf) {
        hipMemsetAsync(lmi, 0, R*4, stream); hipMemsetAsync(lsi, 0, R*4, stream);
        hipMemsetAsync(lmj, 0, R*4, stream); hipMemsetAsync(lsj, 0, R*4, stream);
        hipMemsetAsync(lm2, 0, R*4, stream); hipMemsetAsync(ls2, 0, R*4, stream);
        hipMemsetAsync(obuf, 0, (size_t)R*RH*4, stream);
        k_segmax   <<<CDIV(LGE,256),256,0,stream>>>(val, iiE, lmi, LGE);
        k_segmax   <<<CDIV(LGE,256),256,0,stream>>>(val, jjE, lmj, LGE);
        k_segsumexp<<<CDIV(LGE,256),256,0,stream>>>(val, iiE, lmi, lsi, LGE);
        k_segsumexp<<<CDIV(LGE,256),256,0,stream>>>(val, jjE, lmj, lsj, LGE);
        k_lgat_vsum<<<CDIV(LGE,256),256,0,stream>>>(val, jjE, iiE, lmi, lsi, lmj, lsj, vsum, LGE);
        k_segmax   <<<CDIV(LGE,256),256,0,stream>>>(vsum, jjE, lm2, LGE);
        k_segsumexp<<<CDIV(LGE,256),256,0,stream>>>(vsum, jjE, lm2, ls2, LGE);
        k_edge_agg <<<(int)CDIV((long)LGE*64,256),256,0,stream>>>(vsum, lm2, ls2, jjE, iiE, jjE,
                                                                  xrel, RH, obuf, RH, LGE, RH);
        k_relu2d   <<<CDIV((long)R*RH,256),256,0,stream>>>(obuf, R, RH, RH);
    };
    lgat(remb1, jM, iM, mval, mrg);
    lgat(remb2, jT, iT, tval, tri);

    // ===== x_r = highway(mrg, tri, hrw, hrb) =====
    dim3 gridR(CDIV(RH,GBN), CDIV(R,GBM));
    k_gemm<<<gridR,256,0,stream>>>(mrg, RH, hrw, RH, xrg, RH, R, RH, RH);
    k_highway<<<CDIV((long)R*RH,256),256,0,stream>>>(mrg, RH, xrg, RH, tri, RH, hrb, xr, RH, R, RH, 0);

    // relscore[r] = rel_cat[r]·gat_ar
    k_relscore<<<CDIV((long)R*64,256),256,0,stream>>>(mrg, tri, gat_ar, rsc, R, RH);

    // ===== GAT over edge_index_all -> out cols 300..599 (fully fused) =====
    k_rowdot2<<<CDIV((long)N*64,256),256,0,stream>>>(out, OUTC, N, F, gat_ai, gat_aj, sA_, sB_);
    k_gat300<<<gatherGrid,256,0,stream>>>(out, OUTC, sA_, sB_, rsc, jpA, relpA,
                                          rowptrA, cntA, out+300, OUTC, N);

    // ===== gat_r_to_e over edge_index -> out cols 600..799 (fully fused) =====
    k_rowdot2<<<CDIV((long)N*64,256),256,0,stream>>>(out, OUTC, N, 2*F, g2e_ah, g2e_at, sA_, sB_);
    k_rowdot2<<<CDIV((long)R*64,256),256,0,stream>>>(xr, RH, R, RH, g2e_ar, (const float*)nullptr,
                                                     srel, (float*)nullptr);
    k_gather_rel100<<<gatherGrid,256,0,stream>>>(xr, sA_, srel, relpH, rowptrH, cntH,
                                                 out+600, OUTC, N);
    k_gather_rel100<<<gatherGrid,256,0,stream>>>(xr, sB_, srel, relpT, rowptrT, cntT,
                                                 out+700, OUTC, N);
}

// Round 7
// 2156.392 us; speedup vs baseline: 1.1440x; 1.1440x over previous
//
#include <hip/hip_runtime.h>

#define WAVE 64
#define CDIV(a,b) (((a)+(b)-1)/(b))

typedef float f32x16 __attribute__((ext_vector_type(16)));
typedef unsigned short u16x8 __attribute__((ext_vector_type(8)));

// ---------- bf16 helpers: hi = truncate, lo = rne(residual) ----------
__device__ __forceinline__ unsigned short f2bf_rne(float f) {
    unsigned u = __float_as_uint(f);
    unsigned r = (u + 0x7FFFu + ((u >> 16) & 1u)) >> 16;
    return (unsigned short)r;
}
__device__ __forceinline__ float bf2f(unsigned short h) {
    return __uint_as_float(((unsigned)h) << 16);
}

#define MFMA32(acc, a, b) \
    asm volatile("v_mfma_f32_32x32x16_bf16 %0, %1, %2, %0" : "+v"(acc) : "v"(a), "v"(b))

// ---------- monotonic float<->uint encoding for atomicMax on floats ----------
__device__ __forceinline__ unsigned f2mono(float f) {
    unsigned u = __float_as_uint(f);
    return (u & 0x80000000u) ? ~u : (u | 0x80000000u);
}
__device__ __forceinline__ float mono2f(unsigned u) {
    return (u & 0x80000000u) ? __uint_as_float(u & 0x7fffffffu) : __uint_as_float(~u);
}
__device__ __forceinline__ float leaky(float v) { return (v > 0.0f) ? v : 0.01f*v; }

// fragment-pack offset: matrix row r, col k -> packed short index.
// Layout: [rowtile rt=r>>5][kstep t=k>>4] block of 512 shorts:
//   ((k>>3)&1)*256 + (r&31)*8 + (k&7)
// A wave's MFMA fragment (lane l <- X[row=l&31][k=(l>>5)*8+j]) is then the
// contiguous 16B at block*512 + lane*8 -> direct coalesced global load.
__device__ __forceinline__ long fragoff(long r, int k, int npk) {
    return ((r >> 5) * (long)npk + (k >> 4)) * 512
         + (((k >> 3) & 1) << 8) + ((r & 31) << 3) + (k & 7);
}

// =========================================================================
// k_cvt_pack: f32 [rows][K] (stride ld) -> fragment-packed bf16 hi/lo,
// k-pad (K..npk*16) zeroed. Rows beyond `rows` must be pre-zeroed by memset.
// =========================================================================
__global__ void k_cvt_pack(const float* __restrict__ src, long ld, int rows, int K, int npk,
                           unsigned short* __restrict__ hi, unsigned short* __restrict__ lo)
{
    int nc4 = npk << 2;
    long idx = (long)blockIdx.x*blockDim.x + threadIdx.x;
    if (idx >= (long)rows * nc4) return;
    long r = idx / nc4; int k = (int)(idx % nc4) << 2;
    float4 v = {0.0f, 0.0f, 0.0f, 0.0f};
    if (k + 4 <= K) v = *(const float4*)(src + r*ld + k);
    float vv[4] = {v.x, v.y, v.z, v.w};
    ushort4 h, l;
    unsigned short hh[4], ll[4];
    #pragma unroll
    for (int i = 0; i < 4; ++i) {
        unsigned u = __float_as_uint(vv[i]);
        hh[i] = (unsigned short)(u >> 16);
        ll[i] = f2bf_rne(vv[i] - bf2f(hh[i]));
    }
    h.x = hh[0]; h.y = hh[1]; h.z = hh[2]; h.w = hh[3];
    l.x = ll[0]; l.y = ll[1]; l.z = ll[2]; l.w = ll[3];
    long off = fragoff(r, k, npk);
    *(ushort4*)(hi + off) = h;
    *(ushort4*)(lo + off) = l;
}

// =========================================================================
// k_highway_cvt_pack: out = sig(gl+b)*relu?(x2) + (1-sig)*x1 (f32, stride ldo)
// AND fragment-packed bf16 hi/lo of out. rows must be multiple of 32.
// =========================================================================
__global__ void k_highway_cvt_pack(const float* __restrict__ x1, long ld1,
                                   const float* __restrict__ gl, long ldg,
                                   const float* __restrict__ x2, long ld2,
                                   const float* __restrict__ bias,
                                   float* __restrict__ out, long ldo,
                                   unsigned short* __restrict__ hi,
                                   unsigned short* __restrict__ lo,
                                   int rows, int npk, int relu_x2)
{
    const int nc4 = npk << 2;
    long idx = (long)blockIdx.x*blockDim.x + threadIdx.x;
    if (idx >= (long)rows * nc4) return;
    long r = idx / nc4; int k = (int)(idx % nc4) << 2;
    long off = fragoff(r, k, npk);
    if (k >= 300) {                          // pad chunk
        ushort4 z = {0,0,0,0};
        *(ushort4*)(hi + off) = z;
        *(ushort4*)(lo + off) = z;
        return;
    }
    float4 v1 = *(const float4*)(x1 + r*ld1 + k);
    float4 vg = *(const float4*)(gl + r*ldg + k);
    float4 v2 = *(const float4*)(x2 + r*ld2 + k);
    float4 vb = *(const float4*)(bias + k);
    float o[4];
    float a1[4] = {v1.x, v1.y, v1.z, v1.w};
    float ag[4] = {vg.x, vg.y, vg.z, vg.w};
    float a2[4] = {v2.x, v2.y, v2.z, v2.w};
    float ab[4] = {vb.x, vb.y, vb.z, vb.w};
    ushort4 h, l;
    unsigned short hh[4], ll[4];
    #pragma unroll
    for (int i = 0; i < 4; ++i) {
        float g = 1.0f / (1.0f + expf(-(ag[i] + ab[i])));
        float xv = relu_x2 ? fmaxf(a2[i], 0.0f) : a2[i];
        o[i] = g*xv + (1.0f - g)*a1[i];
        unsigned u = __float_as_uint(o[i]);
        hh[i] = (unsigned short)(u >> 16);
        ll[i] = f2bf_rne(o[i] - bf2f(hh[i]));
    }
    float4 ov = {o[0], o[1], o[2], o[3]};
    *(float4*)(out + r*ldo + k) = ov;
    h.x = hh[0]; h.y = hh[1]; h.z = hh[2]; h.w = hh[3];
    l.x = ll[0]; l.y = ll[1]; l.z = ll[2]; l.w = ll[3];
    *(ushort4*)(hi + off) = h;
    *(ushort4*)(lo + off) = l;
}

// =========================================================================
// k_gemm_frag: C[M,N'] = A * B^T on fragment-packed bf16 hi/lo.
// NO LDS, NO barriers: each wave loads its MFMA fragments directly from
// global (fully coalesced 16B/lane; B is L2-resident), 1-step register
// pipeline, waves free-run. Block 256 thr = 4 waves; wave = 32 rows x 128
// cols (4 coltiles). bf16x3: AhBh + AlBh + AhBl (~fp32 accuracy).
// =========================================================================
__global__ __launch_bounds__(256, 3)
void k_gemm_frag(const unsigned short* __restrict__ Ahi, const unsigned short* __restrict__ Alo,
                 const unsigned short* __restrict__ Bhi, const unsigned short* __restrict__ Blo,
                 float* __restrict__ C, long ldc, int M, int N, int nk)
{
    const int lane = threadIdx.x & 63;
    const int wid  = threadIdx.x >> 6;
    const int col0 = blockIdx.x * 128;
    const int row0 = blockIdx.y * 128 + wid * 32;

    const long cs = (long)nk * 512;                 // tile-row stride (shorts)
    const unsigned short* pAh = Ahi + (long)(row0 >> 5) * cs + lane * 8;
    const unsigned short* pAl = Alo + (long)(row0 >> 5) * cs + lane * 8;
    const unsigned short* pBh = Bhi + (long)(col0 >> 5) * cs + lane * 8;
    const unsigned short* pBl = Blo + (long)(col0 >> 5) * cs + lane * 8;

    f32x16 acc[4];
    #pragma unroll
    for (int c = 0; c < 4; ++c) acc[c] = (f32x16)0.0f;

    u16x8 pah, pal, pb0, pb1, pb2, pb3, pl0, pl1, pl2, pl3;
    u16x8 qah, qal, qb0, qb1, qb2, qb3, ql0, ql1, ql2, ql3;

    #define LOADP(t_) { long o = (long)(t_)*512;                                   \
        pah = *(const u16x8*)(pAh + o);        pal = *(const u16x8*)(pAl + o);     \
        pb0 = *(const u16x8*)(pBh + o);        pl0 = *(const u16x8*)(pBl + o);     \
        pb1 = *(const u16x8*)(pBh + cs + o);   pl1 = *(const u16x8*)(pBl + cs + o);\
        pb2 = *(const u16x8*)(pBh + 2*cs + o); pl2 = *(const u16x8*)(pBl + 2*cs + o);\
        pb3 = *(const u16x8*)(pBh + 3*cs + o); pl3 = *(const u16x8*)(pBl + 3*cs + o); }
    #define LOADQ(t_) { long o = (long)(t_)*512;                                   \
        qah = *(const u16x8*)(pAh + o);        qal = *(const u16x8*)(pAl + o);     \
        qb0 = *(const u16x8*)(pBh + o);        ql0 = *(const u16x8*)(pBl + o);     \
        qb1 = *(const u16x8*)(pBh + cs + o);   ql1 = *(const u16x8*)(pBl + cs + o);\
        qb2 = *(const u16x8*)(pBh + 2*cs + o); ql2 = *(const u16x8*)(pBl + 2*cs + o);\
        qb3 = *(const u16x8*)(pBh + 3*cs + o); ql3 = *(const u16x8*)(pBl + 3*cs + o); }
    #define STEPP {                                                                 \
        MFMA32(acc[0], pah, pb0); MFMA32(acc[1], pah, pb1);                         \
        MFMA32(acc[2], pah, pb2); MFMA32(acc[3], pah, pb3);                         \
        MFMA32(acc[0], pal, pb0); MFMA32(acc[1], pal, pb1);                         \
        MFMA32(acc[2], pal, pb2); MFMA32(acc[3], pal, pb3);                         \
        MFMA32(acc[0], pah, pl0); MFMA32(acc[1], pah, pl1);                         \
        MFMA32(acc[2], pah, pl2); MFMA32(acc[3], pah, pl3); }
    #define STEPQ {                                                                 \
        MFMA32(acc[0], qah, qb0); MFMA32(acc[1], qah, qb1);                         \
        MFMA32(acc[2], qah, qb2); MFMA32(acc[3], qah, qb3);                         \
        MFMA32(acc[0], qal, qb0); MFMA32(acc[1], qal, qb1);                         \
        MFMA32(acc[2], qal, qb2); MFMA32(acc[3], qal, qb3);                         \
        MFMA32(acc[0], qah, ql0); MFMA32(acc[1], qah, ql1);                         \
        MFMA32(acc[2], qah, ql2); MFMA32(acc[3], qah, ql3); }

    LOADP(0);
    int t = 0;
    for (;;) {
        bool m1 = (t + 1 < nk);
        if (m1) LOADQ(t + 1);
        STEPP;
        if (!m1) break;
        bool m2 = (t + 2 < nk);
        if (m2) LOADP(t + 2);
        STEPQ;
        if (!m2) break;
        t += 2;
    }
    #undef LOADP
    #undef LOADQ
    #undef STEPP
    #undef STEPQ

    // epilogue: C/D layout col=lane&31, row=(reg&3)+8*(reg>>2)+4*(lane>>5)
    const int crow0 = row0 + 4*(lane >> 5);
    const int ccol0 = col0 + (lane & 31);
    #pragma unroll
    for (int c = 0; c < 4; ++c) {
        int col = ccol0 + c*32;
        if (col >= N) continue;
        #pragma unroll
        for (int reg = 0; reg < 16; ++reg) {
            int row = crow0 + (reg & 3) + 8*(reg >> 2);
            if (row < M) C[(long)row*ldc + col] = acc[c][reg];
        }
    }
}

// ---------- small f32 GEMM (tiny R x RH highway gate) ----------
#define GBM 64
#define GBN 64
#define GBK 16
__global__ __launch_bounds__(256)
void k_gemm(const float* __restrict__ A, long lda,
            const float* __restrict__ B, long ldb,
            float* __restrict__ C, long ldc,
            int M, int N, int K)
{
    __shared__ float As[GBK][GBM + 4];
    __shared__ float Bs[GBK][GBN + 4];
    const int tid = threadIdx.x;
    const int tx = tid & 15, ty = tid >> 4;
    const int row0 = blockIdx.y * GBM, col0 = blockIdx.x * GBN;
    float acc[4][4] = {};
    for (int kt = 0; kt < K; kt += GBK) {
        #pragma unroll
        for (int p = 0; p < 4; ++p) {
            int mn = (tid >> 4) + p * 16;
            int k  = tid & 15;
            int gk = kt + k;
            int gr = row0 + mn;
            As[k][mn] = (gr < M && gk < K) ? A[(long)gr * lda + gk] : 0.0f;
            int gc = col0 + mn;
            Bs[k][mn] = (gc < N && gk < K) ? B[(long)gc * ldb + gk] : 0.0f;
        }
        __syncthreads();
        #pragma unroll
        for (int kk = 0; kk < GBK; ++kk) {
            float a0 = As[kk][ty*4+0], a1 = As[kk][ty*4+1];
            float a2 = As[kk][ty*4+2], a3 = As[kk][ty*4+3];
            float b0 = Bs[kk][tx*4+0], b1 = Bs[kk][tx*4+1];
            float b2 = Bs[kk][tx*4+2], b3 = Bs[kk][tx*4+3];
            acc[0][0] += a0*b0; acc[0][1] += a0*b1; acc[0][2] += a0*b2; acc[0][3] += a0*b3;
            acc[1][0] += a1*b0; acc[1][1] += a1*b1; acc[1][2] += a1*b2; acc[1][3] += a1*b3;
            acc[2][0] += a2*b0; acc[2][1] += a2*b1; acc[2][2] += a2*b2; acc[2][3] += a2*b3;
            acc[3][0] += a3*b0; acc[3][1] += a3*b1; acc[3][2] += a3*b2; acc[3][3] += a3*b3;
        }
        __syncthreads();
    }
    #pragma unroll
    for (int i2 = 0; i2 < 4; ++i2)
        #pragma unroll
        for (int j2 = 0; j2 < 4; ++j2) {
            int r = row0 + ty*4 + i2, c = col0 + tx*4 + j2;
            if (r < M && c < N) C[(long)r*ldc + c] = acc[i2][j2];
        }
}

// ================= CSR build: histogram -> scan -> fill =================
__global__ void k_hist(const int* __restrict__ key, int* __restrict__ cnt, int E) {
    int e = blockIdx.x*blockDim.x + threadIdx.x;
    if (e < E) atomicAdd(&cnt[key[e]], 1);
}
__global__ void k_scan1(const int* __restrict__ in, int* __restrict__ out,
                        int* __restrict__ bsum, int n) {
    __shared__ int sh[256];
    int gid = blockIdx.x*256 + threadIdx.x;
    int v = (gid < n) ? in[gid] : 0;
    sh[threadIdx.x] = v; __syncthreads();
    for (int o = 1; o < 256; o <<= 1) {
        int t = (threadIdx.x >= o) ? sh[threadIdx.x - o] : 0;
        __syncthreads();
        sh[threadIdx.x] += t;
        __syncthreads();
    }
    if (gid < n) out[gid] = sh[threadIdx.x] - v;      // exclusive
    if (threadIdx.x == 255) bsum[blockIdx.x] = sh[255];
}
__global__ void k_scan2(int* __restrict__ bsum, int nb) {   // single block, nb <= 1024
    __shared__ int sh[1024];
    int v = (threadIdx.x < nb) ? bsum[threadIdx.x] : 0;
    sh[threadIdx.x] = v; __syncthreads();
    for (int o = 1; o < 1024; o <<= 1) {
        int t = (threadIdx.x >= o) ? sh[threadIdx.x - o] : 0;
        __syncthreads();
        sh[threadIdx.x] += t;
        __syncthreads();
    }
    if (threadIdx.x < nb) bsum[threadIdx.x] = sh[threadIdx.x] - v;  // exclusive
}
__global__ void k_scan3(int* __restrict__ out, const int* __restrict__ bsum, int n) {
    int gid = blockIdx.x*256 + threadIdx.x;
    if (gid < n) out[gid] += bsum[blockIdx.x];
}
__global__ void k_fill(const int* __restrict__ key, const int* __restrict__ rowptr,
                       int* __restrict__ cursor, int* __restrict__ perm, int E) {
    int e = blockIdx.x*blockDim.x + threadIdx.x;
    if (e >= E) return;
    int k = key[e];
    int p = rowptr[k] + atomicAdd(&cursor[k], 1);
    perm[p] = e;
}
__global__ void k_dinv_cnt(const int* __restrict__ cnt, float* __restrict__ dinv, int n) {
    int i = blockIdx.x*blockDim.x + threadIdx.x;
    if (i < n) { int c = cnt[i]; dinv[i] = (c > 0) ? rsqrtf((float)c) : 0.0f; }
}

// ---------- CSR-order pre-permutation ----------
__global__ void k_prep_gcn(const int* __restrict__ perm, const int* __restrict__ jA,
                           const int* __restrict__ iA, const float* __restrict__ dinv,
                           int* __restrict__ jp, float* __restrict__ nm, int E) {
    int p = blockIdx.x*blockDim.x + threadIdx.x;
    if (p >= E) return;
    int e = perm[p];
    int j = jA[e];
    jp[p] = j;
    nm[p] = dinv[iA[e]] * dinv[j];
}
__global__ void k_permute_i32(const int* __restrict__ src, const int* __restrict__ perm,
                              int* __restrict__ dst, int E) {
    int p = blockIdx.x*blockDim.x + threadIdx.x;
    if (p < E) dst[p] = src[perm[p]];
}
__global__ void k_permute_mod(const int* __restrict__ src, const int* __restrict__ perm,
                              int* __restrict__ dst, int E, int mod) {
    int p = blockIdx.x*blockDim.x + threadIdx.x;
    if (p < E) dst[p] = src[perm[p]] % mod;
}

// ============ gather aggregations (wave per destination node, F=300) ============
__global__ void k_gather300(const float* __restrict__ x, long ldx,
                            const int* __restrict__ jp, const float* __restrict__ nm,
                            const int* __restrict__ rowptr, const int* __restrict__ cnt,
                            float* __restrict__ out, long ldo, int n)
{
    int w = (blockIdx.x*blockDim.x + threadIdx.x) >> 6;
    int lane = threadIdx.x & 63;
    if (w >= n) return;
    int beg = rowptr[w], end = beg + cnt[w];
    const int i0 = lane, i1 = lane + 64, i2 = lane + 128;
    const bool t3 = (lane < 22);
    float2 a0 = {0,0}, a1 = {0,0}, a2 = {0,0};
    int e = beg;
    for (; e + 4 <= end; e += 4) {
        const float2* r0 = (const float2*)(x + (long)jp[e]  *ldx);
        const float2* r1 = (const float2*)(x + (long)jp[e+1]*ldx);
        const float2* r2 = (const float2*)(x + (long)jp[e+2]*ldx);
        const float2* r3 = (const float2*)(x + (long)jp[e+3]*ldx);
        float w0 = nm[e], w1 = nm[e+1], w2 = nm[e+2], w3 = nm[e+3];
        float2 v;
        v = r0[i0]; a0.x += w0*v.x; a0.y += w0*v.y;
        v = r1[i0]; a0.x += w1*v.x; a0.y += w1*v.y;
        v = r2[i0]; a0.x += w2*v.x; a0.y += w2*v.y;
        v = r3[i0]; a0.x += w3*v.x; a0.y += w3*v.y;
        v = r0[i1]; a1.x += w0*v.x; a1.y += w0*v.y;
        v = r1[i1]; a1.x += w1*v.x; a1.y += w1*v.y;
        v = r2[i1]; a1.x += w2*v.x; a1.y += w2*v.y;
        v = r3[i1]; a1.x += w3*v.x; a1.y += w3*v.y;
        if (t3) {
            v = r0[i2]; a2.x += w0*v.x; a2.y += w0*v.y;
            v = r1[i2]; a2.x += w1*v.x; a2.y += w1*v.y;
            v = r2[i2]; a2.x += w2*v.x; a2.y += w2*v.y;
            v = r3[i2]; a2.x += w3*v.x; a2.y += w3*v.y;
        }
    }
    for (; e < end; ++e) {
        const float2* r0 = (const float2*)(x + (long)jp[e]*ldx);
        float w0 = nm[e];
        float2 v;
        v = r0[i0]; a0.x += w0*v.x; a0.y += w0*v.y;
        v = r0[i1]; a1.x += w0*v.x; a1.y += w0*v.y;
        if (t3) { v = r0[i2]; a2.x += w0*v.x; a2.y += w0*v.y; }
    }
    float2* dst = (float2*)(out + (long)w*ldo);
    dst[i0] = a0; dst[i1] = a1;
    if (t3) dst[i2] = a2;
}

// GAT: fused edge score + segment softmax + weighted gather + relu (F=300)
__global__ void k_gat300(const float* __restrict__ x, long ldx,
                         const float* __restrict__ sA, const float* __restrict__ sB,
                         const float* __restrict__ rsc,
                         const int* __restrict__ jp, const int* __restrict__ relp,
                         const int* __restrict__ rowptr, const int* __restrict__ cnt,
                         float* __restrict__ out, long ldo, int n)
{
    int w = (blockIdx.x*blockDim.x + threadIdx.x) >> 6;
    int lane = threadIdx.x & 63;
    if (w >= n) return;
    int beg = rowptr[w], c = cnt[w];
    const int i0 = lane, i1 = lane + 64, i2 = lane + 128;
    const bool t3 = (lane < 22);
    float2 a0 = {0,0}, a1 = {0,0}, a2 = {0,0};
    if (c > 0) {
        float base = sA[w];
        int   jc = 0;
        float sval = -3.4e38f;
        if (lane < c) {
            jc = jp[beg + lane];
            sval = leaky(base + sB[jc] + rsc[relp[beg + lane]]);
        }
        float mx = sval;
        for (int t = 64 + lane; t < c; t += 64)
            mx = fmaxf(mx, leaky(base + sB[jp[beg+t]] + rsc[relp[beg+t]]));
        #pragma unroll
        for (int o = 32; o > 0; o >>= 1) mx = fmaxf(mx, __shfl_xor(mx, o));
        float pexp = (lane < c) ? expf(sval - mx) : 0.0f;
        float ss = pexp;
        for (int t = 64 + lane; t < c; t += 64)
            ss += expf(leaky(base + sB[jp[beg+t]] + rsc[relp[beg+t]]) - mx);
        #pragma unroll
        for (int o = 32; o > 0; o >>= 1) ss += __shfl_xor(ss, o);
        float inv = 1.0f / (ss + 1e-16f);
        int q = 0;
        int cc = (c < 64) ? c : 64;
        for (; q + 4 <= cc; q += 4) {
            float al0 = __shfl(pexp, q)   * inv;
            float al1 = __shfl(pexp, q+1) * inv;
            float al2 = __shfl(pexp, q+2) * inv;
            float al3 = __shfl(pexp, q+3) * inv;
            long  j0 = __shfl(jc, q), j1 = __shfl(jc, q+1);
            long  j2 = __shfl(jc, q+2), j3 = __shfl(jc, q+3);
            const float2* r0 = (const float2*)(x + j0*ldx);
            const float2* r1 = (const float2*)(x + j1*ldx);
            const float2* r2 = (const float2*)(x + j2*ldx);
            const float2* r3 = (const float2*)(x + j3*ldx);
            float2 v;
            v = r0[i0]; a0.x += al0*v.x; a0.y += al0*v.y;
            v = r1[i0]; a0.x += al1*v.x; a0.y += al1*v.y;
            v = r2[i0]; a0.x += al2*v.x; a0.y += al2*v.y;
            v = r3[i0]; a0.x += al3*v.x; a0.y += al3*v.y;
            v = r0[i1]; a1.x += al0*v.x; a1.y += al0*v.y;
            v = r1[i1]; a1.x += al1*v.x; a1.y += al1*v.y;
            v = r2[i1]; a1.x += al2*v.x; a1.y += al2*v.y;
            v = r3[i1]; a1.x += al3*v.x; a1.y += al3*v.y;
            if (t3) {
                v = r0[i2]; a2.x += al0*v.x; a2.y += al0*v.y;
                v = r1[i2]; a2.x += al1*v.x; a2.y += al1*v.y;
                v = r2[i2]; a2.x += al2*v.x; a2.y += al2*v.y;
                v = r3[i2]; a2.x += al3*v.x; a2.y += al3*v.y;
            }
        }
        for (; q < c; ++q) {
            float al; long j0;
            if (q < 64) { al = __shfl(pexp, q) * inv; j0 = __shfl(jc, q); }
            else {
                j0 = jp[beg + q];
                al = expf(leaky(base + sB[(int)j0] + rsc[relp[beg+q]]) - mx) * inv;
            }
            const float2* r0 = (const float2*)(x + j0*ldx);
            float2 v;
            v = r0[i0]; a0.x += al*v.x; a0.y += al*v.y;
            v = r0[i1]; a1.x += al*v.x; a1.y += al*v.y;
            if (t3) { v = r0[i2]; a2.x += al*v.x; a2.y += al*v.y; }
        }
    }
    float2* dst = (float2*)(out + (long)w*ldo);
    a0.x = fmaxf(a0.x, 0.0f); a0.y = fmaxf(a0.y, 0.0f);
    a1.x = fmaxf(a1.x, 0.0f); a1.y = fmaxf(a1.y, 0.0f);
    dst[i0] = a0; dst[i1] = a1;
    if (t3) { a2.x = fmaxf(a2.x, 0.0f); a2.y = fmaxf(a2.y, 0.0f); dst[i2] = a2; }
}

// r2e: fused score = leaky(snode[w] + srel[relp]) + softmax + gather of xr (F=100)
__global__ void k_gather_rel100(const float* __restrict__ xr,
                                const float* __restrict__ snode,
                                const float* __restrict__ srel,
                                const int* __restrict__ relp,
                                const int* __restrict__ rowptr, const int* __restrict__ cnt,
                                float* __restrict__ out, long ldo, int n)
{
    int w = (blockIdx.x*blockDim.x + threadIdx.x) >> 6;
    int lane = threadIdx.x & 63;
    if (w >= n) return;
    int beg = rowptr[w], c = cnt[w];
    const bool t0 = (lane < 50);
    float2 a0 = {0,0};
    if (c > 0) {
        float base = snode[w];
        int   rc = 0;
        float sval = -3.4e38f;
        if (lane < c) {
            rc = relp[beg + lane];
            sval = leaky(base + srel[rc]);
        }
        float mx = sval;
        for (int t = 64 + lane; t < c; t += 64)
            mx = fmaxf(mx, leaky(base + srel[relp[beg+t]]));
        #pragma unroll
        for (int o = 32; o > 0; o >>= 1) mx = fmaxf(mx, __shfl_xor(mx, o));
        float pexp = (lane < c) ? expf(sval - mx) : 0.0f;
        float ss = pexp;
        for (int t = 64 + lane; t < c; t += 64)
            ss += expf(leaky(base + srel[relp[beg+t]]) - mx);
        #pragma unroll
        for (int o = 32; o > 0; o >>= 1) ss += __shfl_xor(ss, o);
        float inv = 1.0f / (ss + 1e-16f);
        int q = 0;
        int cc = (c < 64) ? c : 64;
        for (; q + 4 <= cc; q += 4) {
            float al0 = __shfl(pexp, q)   * inv;
            float al1 = __shfl(pexp, q+1) * inv;
            float al2 = __shfl(pexp, q+2) * inv;
            float al3 = __shfl(pexp, q+3) * inv;
            long r0i = __shfl(rc, q), r1i = __shfl(rc, q+1);
            long r2i = __shfl(rc, q+2), r3i = __shfl(rc, q+3);
            if (t0) {
                float2 v;
                v = ((const float2*)(xr + r0i*100))[lane]; a0.x += al0*v.x; a0.y += al0*v.y;
                v = ((const float2*)(xr + r1i*100))[lane]; a0.x += al1*v.x; a0.y += al1*v.y;
                v = ((const float2*)(xr + r2i*100))[lane]; a0.x += al2*v.x; a0.y += al2*v.y;
                v = ((const float2*)(xr + r3i*100))[lane]; a0.x += al3*v.x; a0.y += al3*v.y;
            }
        }
        for (; q < c; ++q) {
            float al; long r0i;
            if (q < 64) { al = __shfl(pexp, q) * inv; r0i = __shfl(rc, q); }
            else {
                r0i = relp[beg + q];
                al = expf(leaky(base + srel[(int)r0i]) - mx) * inv;
            }
            if (t0) {
                float2 v = ((const float2*)(xr + r0i*100))[lane];
                a0.x += al*v.x; a0.y += al*v.y;
            }
        }
    }
    if (t0) ((float2*)(out + (long)w*ldo))[lane] = a0;
}

// ---------- highway combine ----------
__global__ void k_highway(const float* __restrict__ x1, long ld1,
                          const float* __restrict__ gl, long ldg,
                          const float* __restrict__ x2, long ld2,
                          const float* __restrict__ bias,
                          float* __restrict__ out, long ldo,
                          long rows, int F, int relu_x2)
{
    long idx = (long)blockIdx.x*blockDim.x + threadIdx.x;
    if (idx >= rows * (long)F) return;
    long r = idx / F; int c = (int)(idx % F);
    float g = 1.0f / (1.0f + expf(-(gl[r*ldg+c] + bias[c])));
    float v2 = x2[r*ld2+c]; if (relu_x2) v2 = fmaxf(v2, 0.0f);
    float v1 = x1[r*ld1+c];
    out[r*ldo+c] = g*v2 + (1.0f-g)*v1;
}

// ---------- segment softmax building blocks (small l_gat path only) ----------
__global__ void k_segmax(const float* __restrict__ ev, const int* __restrict__ idx,
                         unsigned* __restrict__ m, int E) {
    int e = blockIdx.x*blockDim.x + threadIdx.x;
    if (e < E) atomicMax(&m[idx[e]], f2mono(ev[e]));
}
__global__ void k_segsumexp(const float* __restrict__ ev, const int* __restrict__ idx,
                            const unsigned* __restrict__ m, float* __restrict__ s, int E) {
    int e = blockIdx.x*blockDim.x + threadIdx.x;
    if (e < E) atomicAdd(&s[idx[e]], expf(ev[e] - mono2f(m[idx[e]])));
}
__global__ void k_lgat_vsum(const float* __restrict__ val,
                            const int* __restrict__ jj, const int* __restrict__ ii,
                            const unsigned* __restrict__ mi, const float* __restrict__ si,
                            const unsigned* __restrict__ mj, const float* __restrict__ sj,
                            float* __restrict__ vsum, int E)
{
    int e = blockIdx.x*blockDim.x + threadIdx.x;
    if (e >= E) return;
    float v = val[e];
    int i = ii[e], j = jj[e];
    float pi = expf(v - mono2f(mi[i])) / (si[i] + 1e-16f);
    float pj = expf(v - mono2f(mj[j])) / (sj[j] + 1e-16f);
    vsum[e] = pi + pj;
}
__global__ void k_edge_agg(const float* __restrict__ ev,
                           const unsigned* __restrict__ m, const float* __restrict__ s,
                           const int* __restrict__ ka, const int* __restrict__ ko,
                           const int* __restrict__ ks,
                           const float* __restrict__ x, long ldx,
                           float* __restrict__ out, long ldo,
                           int E, int F)
{
    int w = (blockIdx.x*blockDim.x + threadIdx.x) >> 6;
    int lane = threadIdx.x & 63;
    if (w >= E) return;
    int a = ka[w];
    float alpha = expf(ev[w] - mono2f(m[a])) / (s[a] + 1e-16f);
    const float4* src = (const float4*)(x + (long)ks[w]*ldx);
    float* dst = out + (long)ko[w]*ldo;
    int nf4 = F >> 2;
    for (int f = lane; f < nf4; f += WAVE) {
        float4 v = src[f];
        atomicAdd(&dst[f*4+0], alpha*v.x);
        atomicAdd(&dst[f*4+1], alpha*v.y);
        atomicAdd(&dst[f*4+2], alpha*v.z);
        atomicAdd(&dst[f*4+3], alpha*v.w);
    }
}
__global__ void k_relu2d(float* __restrict__ p, long rows, int cols, long ld) {
    long idx = (long)blockIdx.x*blockDim.x + threadIdx.x;
    if (idx >= rows*(long)cols) return;
    long r = idx / cols; int c = (int)(idx % cols);
    float v = p[r*ld+c];
    p[r*ld+c] = fmaxf(v, 0.0f);
}

// ---------- row dots ----------
__global__ void k_rowdot2(const float* __restrict__ x, long ldx, int rows, int K,
                          const float* __restrict__ a, const float* __restrict__ b,
                          float* __restrict__ oa, float* __restrict__ ob)
{
    int w = (blockIdx.x*blockDim.x + threadIdx.x) >> 6;
    int lane = threadIdx.x & 63;
    if (w >= rows) return;
    const float* xr = x + (long)w*ldx;
    float sa = 0.0f, sb = 0.0f;
    for (int k = lane; k < K; k += WAVE) {
        float v = xr[k];
        sa += v * a[k];
        if (b) sb += v * b[k];
    }
    #pragma unroll
    for (int off = 32; off > 0; off >>= 1) {
        sa += __shfl_down(sa, off);
        if (b) sb += __shfl_down(sb, off);
    }
    if (lane == 0) { oa[w] = sa; if (ob) ob[w] = sb; }
}

// ---------- relscore[r] = merge[r]·ar[0:RH] + tri[r]·ar[RH:2RH] ----------
__global__ void k_relscore(const float* __restrict__ mg, const float* __restrict__ tr,
                           const float* __restrict__ ar, float* __restrict__ out, int R, int RH)
{
    int w = (blockIdx.x*blockDim.x + threadIdx.x) >> 6;
    int lane = threadIdx.x & 63;
    if (w >= R) return;
    float s = 0.0f;
    for (int k = lane; k < RH; k += WAVE)
        s += mg[(long)w*RH+k]*ar[k] + tr[(long)w*RH+k]*ar[RH+k];
    #pragma unroll
    for (int off = 32; off > 0; off >>= 1) s += __shfl_down(s, off);
    if (lane == 0) out[w] = s;
}

extern "C" void kernel_launch(void* const* d_in, const int* in_sizes, int n_in,
                              void* d_out, int out_size, void* d_ws, size_t ws_size,
                              hipStream_t stream)
{
    const float* x_e   = (const float*)d_in[0];
    const float* mval  = (const float*)d_in[1];
    const float* tval  = (const float*)d_in[2];
    const float* g1w   = (const float*)d_in[3];
    const float* h1w   = (const float*)d_in[4];
    const float* h1b   = (const float*)d_in[5];
    const float* g2w   = (const float*)d_in[6];
    const float* h2w   = (const float*)d_in[7];
    const float* h2b   = (const float*)d_in[8];
    const float* remb1 = (const float*)d_in[9];
    const float* remb2 = (const float*)d_in[10];
    const float* hrw   = (const float*)d_in[11];
    const float* hrb   = (const float*)d_in[12];
    const float* gat_ai= (const float*)d_in[13];
    const float* gat_aj= (const float*)d_in[14];
    const float* gat_ar= (const float*)d_in[15];
    const float* g2e_ah= (const float*)d_in[16];
    const float* g2e_at= (const float*)d_in[17];
    const float* g2e_ar= (const float*)d_in[18];
    const int* edge_index     = (const int*)d_in[19];
    const int* rel            = (const int*)d_in[20];
    const int* edge_index_all = (const int*)d_in[21];
    const int* rel_all        = (const int*)d_in[22];
    const int* lg_merge       = (const int*)d_in[23];
    const int* lg_tri         = (const int*)d_in[24];

    const int F    = 300;
    const int RH   = 100;
    const int Kp   = 304;                  // padded K
    const int npk  = Kp / 16;              // 19 k-steps
    const int N    = in_sizes[0] / F;      // 100000 (multiple of 32)
    const int E    = in_sizes[20];         // 400000
    const int EA   = in_sizes[22];         // 800000
    const int LGE  = in_sizes[1];          // 60000
    const int R    = in_sizes[9] / RH;     // 2000
    const long OUTC = 800;
    const int Mpad = CDIV(N, 128) * 128;   // 100096
    const int Npad = 384;                  // 12 coltiles of 32

    const int* jA = edge_index_all;
    const int* iA = edge_index_all + EA;
    const int* hE = edge_index;
    const int* tE = edge_index + E;
    const int* jM = lg_merge;  const int* iM = lg_merge + LGE;
    const int* jT = lg_tri;    const int* iT = lg_tri  + LGE;

    float* ws = (float*)d_ws;
    size_t off = 0;
    auto alloc = [&](size_t n) { float* p = ws + off; off += (n + 3) & ~(size_t)3; return p; };
    float*    Ascr = alloc((size_t)N*F);                       // GEMM output scratch f32
    unsigned short* Axh = (unsigned short*)alloc((size_t)Mpad*Kp/2);  // A packed hi
    unsigned short* Axl = (unsigned short*)alloc((size_t)Mpad*Kp/2);  // A packed lo
    unsigned short* Wh[4]; unsigned short* Wl[4];
    for (int i = 0; i < 4; ++i) {
        Wh[i] = (unsigned short*)alloc((size_t)Npad*Kp/2);
        Wl[i] = (unsigned short*)alloc((size_t)Npad*Kp/2);
    }
    float*    dinv = alloc(N);
    float*    sA_  = alloc(N);
    float*    sB_  = alloc(N);
    float*    mrg  = alloc((size_t)R*RH);
    float*    tri  = alloc((size_t)R*RH);
    float*    xr   = alloc((size_t)R*RH);
    float*    xrg  = alloc((size_t)R*RH);
    unsigned* lmi  = (unsigned*)alloc(R);  float* lsi = alloc(R);
    unsigned* lmj  = (unsigned*)alloc(R);  float* lsj = alloc(R);
    unsigned* lm2  = (unsigned*)alloc(R);  float* ls2 = alloc(R);
    float*    vsum = alloc(LGE);
    float*    rsc  = alloc(R);
    float*    srel = alloc(R);
    int*   bsum    = (int*)alloc(1024);
    int*   cursor  = (int*)alloc(N);
    int*   rowptrA = (int*)alloc(N); int* cntA = (int*)alloc(N); int* permA = (int*)alloc(EA);
    int*   rowptrH = (int*)alloc(N); int* cntH = (int*)alloc(N); int* permH = (int*)alloc(E);
    int*   rowptrT = (int*)alloc(N); int* cntT = (int*)alloc(N); int* permT = (int*)alloc(E);
    int*   jpA     = (int*)alloc(EA);
    float* nmA     = alloc(EA);
    int*   relpA   = (int*)alloc(EA);
    int*   relpH   = (int*)alloc(E);
    int*   relpT   = (int*)alloc(E);

    float* out = (float*)d_out;              // [N, 800]

    const long NF = (long)N * F;
    const int  nb = CDIV(N, 256);
    dim3 gemmGrid(3, CDIV(N, 128));          // col fastest
    const int gatherGrid = CDIV(N, 4);
    const int cvtBigGrid = CDIV((long)N * (Kp/4), 256);
    const int cvtWGrid   = CDIV(300 * (Kp/4), 256);

    auto build_csr = [&](const int* key, int E_, int* rowptr, int* cnt, int* perm) {
        hipMemsetAsync(cnt, 0, (size_t)N*4, stream);
        k_hist<<<CDIV(E_,256),256,0,stream>>>(key, cnt, E_);
        k_scan1<<<nb,256,0,stream>>>(cnt, rowptr, bsum, N);
        k_scan2<<<1,1024,0,stream>>>(bsum, nb);
        k_scan3<<<nb,256,0,stream>>>(rowptr, bsum, N);
        hipMemsetAsync(cursor, 0, (size_t)N*4, stream);
        k_fill<<<CDIV(E_,256),256,0,stream>>>(key, rowptr, cursor, perm, E_);
    };

    // ===== zero pad regions, then fragment-pack converts =====
    for (int i = 0; i < 4; ++i) {
        hipMemsetAsync(Wh[i], 0, (size_t)Npad*Kp*2, stream);
        hipMemsetAsync(Wl[i], 0, (size_t)Npad*Kp*2, stream);
    }
    // A pad rowtiles (rows N..Mpad; N multiple of 32 -> clean tile boundary)
    hipMemsetAsync(Axh + (size_t)N*Kp, 0, (size_t)(Mpad-N)*Kp*2, stream);
    hipMemsetAsync(Axl + (size_t)N*Kp, 0, (size_t)(Mpad-N)*Kp*2, stream);
    k_cvt_pack<<<cvtWGrid,256,0,stream>>>(g1w, 300, 300, 300, npk, Wh[0], Wl[0]);
    k_cvt_pack<<<cvtWGrid,256,0,stream>>>(h1w, 300, 300, 300, npk, Wh[1], Wl[1]);
    k_cvt_pack<<<cvtWGrid,256,0,stream>>>(g2w, 300, 300, 300, npk, Wh[2], Wl[2]);
    k_cvt_pack<<<cvtWGrid,256,0,stream>>>(h2w, 300, 300, 300, npk, Wh[3], Wl[3]);
    k_cvt_pack<<<cvtBigGrid,256,0,stream>>>(x_e, 300, N, 300, npk, Axh, Axl);

    // ===== CSRs + pre-permutes =====
    build_csr(iA, EA, rowptrA, cntA, permA);
    build_csr(hE, E,  rowptrH, cntH, permH);
    build_csr(tE, E,  rowptrT, cntT, permT);
    k_dinv_cnt<<<CDIV(N,256),256,0,stream>>>(cntA, dinv, N);
    k_prep_gcn<<<CDIV(EA,256),256,0,stream>>>(permA, jA, iA, dinv, jpA, nmA, EA);
    k_permute_mod<<<CDIV(EA,256),256,0,stream>>>(rel_all, permA, relpA, EA, R);
    k_permute_i32<<<CDIV(E,256),256,0,stream>>>(rel, permH, relpH, E);
    k_permute_i32<<<CDIV(E,256),256,0,stream>>>(rel, permT, relpT, E);

    // ===== GCN layer 1 + highway (fused with fragment-pack re-convert) =====
    k_gemm_frag<<<gemmGrid,256,0,stream>>>(Axh, Axl, Wh[0], Wl[0], Ascr, F, N, F, npk);
    k_gather300<<<gatherGrid,256,0,stream>>>(Ascr, F, jpA, nmA, rowptrA, cntA, out+300, OUTC, N);
    k_gemm_frag<<<gemmGrid,256,0,stream>>>(Axh, Axl, Wh[1], Wl[1], Ascr, F, N, F, npk);
    k_highway_cvt_pack<<<cvtBigGrid,256,0,stream>>>(x_e, F, Ascr, F, out+300, OUTC, h1b,
                                                    out, OUTC, Axh, Axl, N, npk, 1);

    // ===== GCN layer 2 + highway =====
    k_gemm_frag<<<gemmGrid,256,0,stream>>>(Axh, Axl, Wh[2], Wl[2], Ascr, F, N, F, npk);
    k_gather300<<<gatherGrid,256,0,stream>>>(Ascr, F, jpA, nmA, rowptrA, cntA, out+300, OUTC, N);
    k_gemm_frag<<<gemmGrid,256,0,stream>>>(Axh, Axl, Wh[3], Wl[3], Ascr, F, N, F, npk);
    k_highway<<<CDIV(NF,256),256,0,stream>>>(out, OUTC, Ascr, F, out+300, OUTC, h2b, out, OUTC, N, F, 1);

    // ===== l_gat on the two line graphs (small; atomic path) =====
    auto lgat = [&](const float* xrel, const int* jjE, const int* iiE, const float* val, float* obuf) {
        hipMemsetAsync(lmi, 0, R*4, stream); hipMemsetAsync(lsi, 0, R*4, stream);
        hipMemsetAsync(lmj, 0, R*4, stream); hipMemsetAsync(lsj, 0, R*4, stream);
        hipMemsetAsync(lm2, 0, R*4, stream); hipMemsetAsync(ls2, 0, R*4, stream);
        hipMemsetAsync(obuf, 0, (size_t)R*RH*4, stream);
        k_segmax   <<<CDIV(LGE,256),256,0,stream>>>(val, iiE, lmi, LGE);
        k_segmax   <<<CDIV(LGE,256),256,0,stream>>>(val, jjE, lmj, LGE);
        k_segsumexp<<<CDIV(LGE,256),256,0,stream>>>(val, iiE, lmi, lsi, LGE);
        k_segsumexp<<<CDIV(LGE,256),256,0,stream>>>(val, jjE, lmj, lsj, LGE);
        k_lgat_vsum<<<CDIV(LGE,256),256,0,stream>>>(val, jjE, iiE, lmi, lsi, lmj, lsj, vsum, LGE);
        k_segmax   <<<CDIV(LGE,256),256,0,stream>>>(vsum, jjE, lm2, LGE);
        k_segsumexp<<<CDIV(LGE,256),256,0,stream>>>(vsum, jjE, lm2, ls2, LGE);
        k_edge_agg <<<(int)CDIV((long)LGE*64,256),256,0,stream>>>(vsum, lm2, ls2, jjE, iiE, jjE,
                                                                  xrel, RH, obuf, RH, LGE, RH);
        k_relu2d   <<<CDIV((long)R*RH,256),256,0,stream>>>(obuf, R, RH, RH);
    };
    lgat(remb1, jM, iM, mval, mrg);
    lgat(remb2, jT, iT, tval, tri);

    // ===== x_r = highway(mrg, tri, hrw, hrb) =====
    dim3 gridR(CDIV(RH,GBN), CDIV(R,GBM));
    k_gemm<<<gridR,256,0,stream>>>(mrg, RH, hrw, RH, xrg, RH, R, RH, RH);
    k_highway<<<CDIV((long)R*RH,256),256,0,stream>>>(mrg, RH, xrg, RH, tri, RH, hrb, xr, RH, R, RH, 0);

    // relscore[r] = rel_cat[r]·gat_ar
    k_relscore<<<CDIV((long)R*64,256),256,0,stream>>>(mrg, tri, gat_ar, rsc, R, RH);

    // ===== GAT over edge_index_all -> out cols 300..599 (fully fused) =====
    k_rowdot2<<<CDIV((long)N*64,256),256,0,stream>>>(out, OUTC, N, F, gat_ai, gat_aj, sA_, sB_);
    k_gat300<<<gatherGrid,256,0,stream>>>(out, OUTC, sA_, sB_, rsc, jpA, relpA,
                                          rowptrA, cntA, out+300, OUTC, N);

    // ===== gat_r_to_e over edge_index -> out cols 600..799 (fully fused) =====
    k_rowdot2<<<CDIV((long)N*64,256),256,0,stream>>>(out, OUTC, N, 2*F, g2e_ah, g2e_at, sA_, sB_);
    k_rowdot2<<<CDIV((long)R*64,256),256,0,stream>>>(xr, RH, R, RH, g2e_ar, (const float*)nullptr,
                                                     srel, (float*)nullptr);
    k_gather_rel100<<<gatherGrid,256,0,stream>>>(xr, sA_, srel, relpH, rowptrH, cntH,
                                                 out+600, OUTC, N);
    k_gather_rel100<<<gatherGrid,256,0,stream>>>(xr, sB_, srel, relpT, rowptrT, cntT,
                                                 out+700, OUTC, N);
}

// Round 8
// 1981.158 us; speedup vs baseline: 1.2452x; 1.0885x over previous
//
#include <hip/hip_runtime.h>

#define WAVE 64
#define CDIV(a,b) (((a)+(b)-1)/(b))

typedef float f32x16 __attribute__((ext_vector_type(16)));
typedef unsigned short u16x8 __attribute__((ext_vector_type(8)));

// ---------- bf16 helpers: hi = truncate, lo = rne(residual) ----------
__device__ __forceinline__ unsigned short f2bf_rne(float f) {
    unsigned u = __float_as_uint(f);
    unsigned r = (u + 0x7FFFu + ((u >> 16) & 1u)) >> 16;
    return (unsigned short)r;
}
__device__ __forceinline__ float bf2f(unsigned short h) {
    return __uint_as_float(((unsigned)h) << 16);
}

#define MFMA32(acc, a, b) \
    asm volatile("v_mfma_f32_32x32x16_bf16 %0, %1, %2, %0" : "+v"(acc) : "v"(a), "v"(b))

// ---------- monotonic float<->uint encoding for atomicMax on floats ----------
__device__ __forceinline__ unsigned f2mono(float f) {
    unsigned u = __float_as_uint(f);
    return (u & 0x80000000u) ? ~u : (u | 0x80000000u);
}
__device__ __forceinline__ float mono2f(unsigned u) {
    return (u & 0x80000000u) ? __uint_as_float(u & 0x7fffffffu) : __uint_as_float(~u);
}
__device__ __forceinline__ float leaky(float v) { return (v > 0.0f) ? v : 0.01f*v; }

// fragment-pack offset: matrix row r, col k -> packed short index.
__device__ __forceinline__ long fragoff(long r, int k, int npk) {
    return ((r >> 5) * (long)npk + (k >> 4)) * 512
         + (((k >> 3) & 1) << 8) + ((r & 31) << 3) + (k & 7);
}

// =========================================================================
// k_cvt_pack: f32 [rows][K] (stride ld) -> fragment-packed bf16 hi/lo at
// packed-row offset roff. k-pad (K..npk*16) zeroed.
// =========================================================================
__global__ void k_cvt_pack(const float* __restrict__ src, long ld, int rows, int K, int npk,
                           int roff,
                           unsigned short* __restrict__ hi, unsigned short* __restrict__ lo)
{
    int nc4 = npk << 2;
    long idx = (long)blockIdx.x*blockDim.x + threadIdx.x;
    if (idx >= (long)rows * nc4) return;
    long r = idx / nc4; int k = (int)(idx % nc4) << 2;
    float4 v = {0.0f, 0.0f, 0.0f, 0.0f};
    if (k + 4 <= K) v = *(const float4*)(src + r*ld + k);
    float vv[4] = {v.x, v.y, v.z, v.w};
    ushort4 h, l;
    unsigned short hh[4], ll[4];
    #pragma unroll
    for (int i = 0; i < 4; ++i) {
        unsigned u = __float_as_uint(vv[i]);
        hh[i] = (unsigned short)(u >> 16);
        ll[i] = f2bf_rne(vv[i] - bf2f(hh[i]));
    }
    h.x = hh[0]; h.y = hh[1]; h.z = hh[2]; h.w = hh[3];
    l.x = ll[0]; l.y = ll[1]; l.z = ll[2]; l.w = ll[3];
    long off = fragoff(r + roff, k, npk);
    *(ushort4*)(hi + off) = h;
    *(ushort4*)(lo + off) = l;
}

// =========================================================================
// k_gemm_frag: C[M,N'] = A * B^T on fragment-packed bf16 hi/lo.
// NO LDS, NO barriers. Block 256 thr = 4 waves; wave = 32 rows x 128 cols.
// bf16x3: AhBh + AlBh + AhBl (~fp32 accuracy).
// =========================================================================
__global__ __launch_bounds__(256, 3)
void k_gemm_frag(const unsigned short* __restrict__ Ahi, const unsigned short* __restrict__ Alo,
                 const unsigned short* __restrict__ Bhi, const unsigned short* __restrict__ Blo,
                 float* __restrict__ C, long ldc, int M, int N, int nk)
{
    const int lane = threadIdx.x & 63;
    const int wid  = threadIdx.x >> 6;
    const int col0 = blockIdx.x * 128;
    const int row0 = blockIdx.y * 128 + wid * 32;

    const long cs = (long)nk * 512;                 // tile-row stride (shorts)
    const unsigned short* pAh = Ahi + (long)(row0 >> 5) * cs + lane * 8;
    const unsigned short* pAl = Alo + (long)(row0 >> 5) * cs + lane * 8;
    const unsigned short* pBh = Bhi + (long)(col0 >> 5) * cs + lane * 8;
    const unsigned short* pBl = Blo + (long)(col0 >> 5) * cs + lane * 8;

    f32x16 acc[4];
    #pragma unroll
    for (int c = 0; c < 4; ++c) acc[c] = (f32x16)0.0f;

    u16x8 pah, pal, pb0, pb1, pb2, pb3, pl0, pl1, pl2, pl3;
    u16x8 qah, qal, qb0, qb1, qb2, qb3, ql0, ql1, ql2, ql3;

    #define LOADP(t_) { long o = (long)(t_)*512;                                   \
        pah = *(const u16x8*)(pAh + o);        pal = *(const u16x8*)(pAl + o);     \
        pb0 = *(const u16x8*)(pBh + o);        pl0 = *(const u16x8*)(pBl + o);     \
        pb1 = *(const u16x8*)(pBh + cs + o);   pl1 = *(const u16x8*)(pBl + cs + o);\
        pb2 = *(const u16x8*)(pBh + 2*cs + o); pl2 = *(const u16x8*)(pBl + 2*cs + o);\
        pb3 = *(const u16x8*)(pBh + 3*cs + o); pl3 = *(const u16x8*)(pBl + 3*cs + o); }
    #define LOADQ(t_) { long o = (long)(t_)*512;                                   \
        qah = *(const u16x8*)(pAh + o);        qal = *(const u16x8*)(pAl + o);     \
        qb0 = *(const u16x8*)(pBh + o);        ql0 = *(const u16x8*)(pBl + o);     \
        qb1 = *(const u16x8*)(pBh + cs + o);   ql1 = *(const u16x8*)(pBl + cs + o);\
        qb2 = *(const u16x8*)(pBh + 2*cs + o); ql2 = *(const u16x8*)(pBl + 2*cs + o);\
        qb3 = *(const u16x8*)(pBh + 3*cs + o); ql3 = *(const u16x8*)(pBl + 3*cs + o); }
    #define STEPP {                                                                 \
        MFMA32(acc[0], pah, pb0); MFMA32(acc[1], pah, pb1);                         \
        MFMA32(acc[2], pah, pb2); MFMA32(acc[3], pah, pb3);                         \
        MFMA32(acc[0], pal, pb0); MFMA32(acc[1], pal, pb1);                         \
        MFMA32(acc[2], pal, pb2); MFMA32(acc[3], pal, pb3);                         \
        MFMA32(acc[0], pah, pl0); MFMA32(acc[1], pah, pl1);                         \
        MFMA32(acc[2], pah, pl2); MFMA32(acc[3], pah, pl3); }
    #define STEPQ {                                                                 \
        MFMA32(acc[0], qah, qb0); MFMA32(acc[1], qah, qb1);                         \
        MFMA32(acc[2], qah, qb2); MFMA32(acc[3], qah, qb3);                         \
        MFMA32(acc[0], qal, qb0); MFMA32(acc[1], qal, qb1);                         \
        MFMA32(acc[2], qal, qb2); MFMA32(acc[3], qal, qb3);                         \
        MFMA32(acc[0], qah, ql0); MFMA32(acc[1], qah, ql1);                         \
        MFMA32(acc[2], qah, ql2); MFMA32(acc[3], qah, ql3); }

    LOADP(0);
    int t = 0;
    for (;;) {
        bool m1 = (t + 1 < nk);
        if (m1) LOADQ(t + 1);
        STEPP;
        if (!m1) break;
        bool m2 = (t + 2 < nk);
        if (m2) LOADP(t + 2);
        STEPQ;
        if (!m2) break;
        t += 2;
    }
    #undef LOADP
    #undef LOADQ
    #undef STEPP
    #undef STEPQ

    const int crow0 = row0 + 4*(lane >> 5);
    const int ccol0 = col0 + (lane & 31);
    #pragma unroll
    for (int c = 0; c < 4; ++c) {
        int col = ccol0 + c*32;
        if (col >= N) continue;
        #pragma unroll
        for (int reg = 0; reg < 16; ++reg) {
            int row = crow0 + (reg & 3) + 8*(reg >> 2);
            if (row < M) C[(long)row*ldc + col] = acc[c][reg];
        }
    }
}

// ---------- small f32 GEMM (tiny R x RH highway gate) ----------
#define GBM 64
#define GBN 64
#define GBK 16
__global__ __launch_bounds__(256)
void k_gemm(const float* __restrict__ A, long lda,
            const float* __restrict__ B, long ldb,
            float* __restrict__ C, long ldc,
            int M, int N, int K)
{
    __shared__ float As[GBK][GBM + 4];
    __shared__ float Bs[GBK][GBN + 4];
    const int tid = threadIdx.x;
    const int tx = tid & 15, ty = tid >> 4;
    const int row0 = blockIdx.y * GBM, col0 = blockIdx.x * GBN;
    float acc[4][4] = {};
    for (int kt = 0; kt < K; kt += GBK) {
        #pragma unroll
        for (int p = 0; p < 4; ++p) {
            int mn = (tid >> 4) + p * 16;
            int k  = tid & 15;
            int gk = kt + k;
            int gr = row0 + mn;
            As[k][mn] = (gr < M && gk < K) ? A[(long)gr * lda + gk] : 0.0f;
            int gc = col0 + mn;
            Bs[k][mn] = (gc < N && gk < K) ? B[(long)gc * ldb + gk] : 0.0f;
        }
        __syncthreads();
        #pragma unroll
        for (int kk = 0; kk < GBK; ++kk) {
            float a0 = As[kk][ty*4+0], a1 = As[kk][ty*4+1];
            float a2 = As[kk][ty*4+2], a3 = As[kk][ty*4+3];
            float b0 = Bs[kk][tx*4+0], b1 = Bs[kk][tx*4+1];
            float b2 = Bs[kk][tx*4+2], b3 = Bs[kk][tx*4+3];
            acc[0][0] += a0*b0; acc[0][1] += a0*b1; acc[0][2] += a0*b2; acc[0][3] += a0*b3;
            acc[1][0] += a1*b0; acc[1][1] += a1*b1; acc[1][2] += a1*b2; acc[1][3] += a1*b3;
            acc[2][0] += a2*b0; acc[2][1] += a2*b1; acc[2][2] += a2*b2; acc[2][3] += a2*b3;
            acc[3][0] += a3*b0; acc[3][1] += a3*b1; acc[3][2] += a3*b2; acc[3][3] += a3*b3;
        }
        __syncthreads();
    }
    #pragma unroll
    for (int i2 = 0; i2 < 4; ++i2)
        #pragma unroll
        for (int j2 = 0; j2 < 4; ++j2) {
            int r = row0 + ty*4 + i2, c = col0 + tx*4 + j2;
            if (r < M && c < N) C[(long)r*ldc + c] = acc[i2][j2];
        }
}

// ================= CSR build: histogram -> scan -> fill =================
__global__ void k_hist(const int* __restrict__ key, int* __restrict__ cnt, int E) {
    int e = blockIdx.x*blockDim.x + threadIdx.x;
    if (e < E) atomicAdd(&cnt[key[e]], 1);
}
__global__ void k_scan1(const int* __restrict__ in, int* __restrict__ out,
                        int* __restrict__ bsum, int n) {
    __shared__ int sh[256];
    int gid = blockIdx.x*256 + threadIdx.x;
    int v = (gid < n) ? in[gid] : 0;
    sh[threadIdx.x] = v; __syncthreads();
    for (int o = 1; o < 256; o <<= 1) {
        int t = (threadIdx.x >= o) ? sh[threadIdx.x - o] : 0;
        __syncthreads();
        sh[threadIdx.x] += t;
        __syncthreads();
    }
    if (gid < n) out[gid] = sh[threadIdx.x] - v;      // exclusive
    if (threadIdx.x == 255) bsum[blockIdx.x] = sh[255];
}
__global__ void k_scan2(int* __restrict__ bsum, int nb) {   // single block, nb <= 1024
    __shared__ int sh[1024];
    int v = (threadIdx.x < nb) ? bsum[threadIdx.x] : 0;
    sh[threadIdx.x] = v; __syncthreads();
    for (int o = 1; o < 1024; o <<= 1) {
        int t = (threadIdx.x >= o) ? sh[threadIdx.x - o] : 0;
        __syncthreads();
        sh[threadIdx.x] += t;
        __syncthreads();
    }
    if (threadIdx.x < nb) bsum[threadIdx.x] = sh[threadIdx.x] - v;  // exclusive
}
__global__ void k_scan3(int* __restrict__ out, const int* __restrict__ bsum, int n) {
    int gid = blockIdx.x*256 + threadIdx.x;
    if (gid < n) out[gid] += bsum[blockIdx.x];
}
__global__ void k_fill(const int* __restrict__ key, const int* __restrict__ rowptr,
                       int* __restrict__ cursor, int* __restrict__ perm, int E) {
    int e = blockIdx.x*blockDim.x + threadIdx.x;
    if (e >= E) return;
    int k = key[e];
    int p = rowptr[k] + atomicAdd(&cursor[k], 1);
    perm[p] = e;
}
__global__ void k_dinv_cnt(const int* __restrict__ cnt, float* __restrict__ dinv, int n) {
    int i = blockIdx.x*blockDim.x + threadIdx.x;
    if (i < n) { int c = cnt[i]; dinv[i] = (c > 0) ? rsqrtf((float)c) : 0.0f; }
}

// ---------- CSR-order pre-permutation ----------
__global__ void k_prep_gcn(const int* __restrict__ perm, const int* __restrict__ jA,
                           const int* __restrict__ iA, const float* __restrict__ dinv,
                           int* __restrict__ jp, float* __restrict__ nm, int E) {
    int p = blockIdx.x*blockDim.x + threadIdx.x;
    if (p >= E) return;
    int e = perm[p];
    int j = jA[e];
    jp[p] = j;
    nm[p] = dinv[iA[e]] * dinv[j];
}
__global__ void k_permute_i32(const int* __restrict__ src, const int* __restrict__ perm,
                              int* __restrict__ dst, int E) {
    int p = blockIdx.x*blockDim.x + threadIdx.x;
    if (p < E) dst[p] = src[perm[p]];
}
__global__ void k_permute_mod(const int* __restrict__ src, const int* __restrict__ perm,
                              int* __restrict__ dst, int E, int mod) {
    int p = blockIdx.x*blockDim.x + threadIdx.x;
    if (p < E) dst[p] = src[perm[p]] % mod;
}

// =========================================================================
// k_gather_hw: fused GCN gather + relu + highway (+ optional bf16 frag-pack).
// Wave per node w:
//   acc = sum nm[p] * xg[jp[p], 0..299]       (xg ld 640, gather)
//   g   = sigmoid(gl[w] + bias); o = g*relu(acc) + (1-g)*x1[w]
//   out[w, 0..299] = o;  if (hi) pack o as bf16 hi/lo fragments (layer-1)
// =========================================================================
__global__ void k_gather_hw(const float* __restrict__ xg, long ldx,
                            const float* __restrict__ gl,
                            const float* __restrict__ x1, long ld1,
                            const float* __restrict__ bias,
                            const int* __restrict__ jp, const float* __restrict__ nm,
                            const int* __restrict__ rowptr, const int* __restrict__ cnt,
                            float* __restrict__ out, long ldo,
                            unsigned short* __restrict__ hi, unsigned short* __restrict__ lo,
                            int npk, int n)
{
    int w = (blockIdx.x*blockDim.x + threadIdx.x) >> 6;
    int lane = threadIdx.x & 63;
    if (w >= n) return;
    int beg = rowptr[w], end = beg + cnt[w];
    const int i0 = lane, i1 = lane + 64, i2 = lane + 128;
    const bool t3 = (lane < 22);
    float2 a0 = {0,0}, a1 = {0,0}, a2 = {0,0};
    int e = beg;
    for (; e + 4 <= end; e += 4) {
        const float2* r0 = (const float2*)(xg + (long)jp[e]  *ldx);
        const float2* r1 = (const float2*)(xg + (long)jp[e+1]*ldx);
        const float2* r2 = (const float2*)(xg + (long)jp[e+2]*ldx);
        const float2* r3 = (const float2*)(xg + (long)jp[e+3]*ldx);
        float w0 = nm[e], w1 = nm[e+1], w2 = nm[e+2], w3 = nm[e+3];
        float2 v;
        v = r0[i0]; a0.x += w0*v.x; a0.y += w0*v.y;
        v = r1[i0]; a0.x += w1*v.x; a0.y += w1*v.y;
        v = r2[i0]; a0.x += w2*v.x; a0.y += w2*v.y;
        v = r3[i0]; a0.x += w3*v.x; a0.y += w3*v.y;
        v = r0[i1]; a1.x += w0*v.x; a1.y += w0*v.y;
        v = r1[i1]; a1.x += w1*v.x; a1.y += w1*v.y;
        v = r2[i1]; a1.x += w2*v.x; a1.y += w2*v.y;
        v = r3[i1]; a1.x += w3*v.x; a1.y += w3*v.y;
        if (t3) {
            v = r0[i2]; a2.x += w0*v.x; a2.y += w0*v.y;
            v = r1[i2]; a2.x += w1*v.x; a2.y += w1*v.y;
            v = r2[i2]; a2.x += w2*v.x; a2.y += w2*v.y;
            v = r3[i2]; a2.x += w3*v.x; a2.y += w3*v.y;
        }
    }
    for (; e < end; ++e) {
        const float2* r0 = (const float2*)(xg + (long)jp[e]*ldx);
        float w0 = nm[e];
        float2 v;
        v = r0[i0]; a0.x += w0*v.x; a0.y += w0*v.y;
        v = r0[i1]; a1.x += w0*v.x; a1.y += w0*v.y;
        if (t3) { v = r0[i2]; a2.x += w0*v.x; a2.y += w0*v.y; }
    }
    // highway: o = sig(gl+b)*relu(acc) + (1-sig)*x1
    const float2* glr = (const float2*)(gl + (long)w*ldx);
    const float2* x1r = (const float2*)(x1 + (long)w*ld1);
    const float2* br  = (const float2*)bias;
    float2* dst = (float2*)(out + (long)w*ldo);
    float2 o0, o1, o2;
    {
        float2 gv = glr[i0], xv = x1r[i0], bv = br[i0];
        float g0 = 1.0f/(1.0f+expf(-(gv.x+bv.x))), g1 = 1.0f/(1.0f+expf(-(gv.y+bv.y)));
        o0.x = g0*fmaxf(a0.x,0.0f) + (1.0f-g0)*xv.x;
        o0.y = g1*fmaxf(a0.y,0.0f) + (1.0f-g1)*xv.y;
        dst[i0] = o0;
    }
    {
        float2 gv = glr[i1], xv = x1r[i1], bv = br[i1];
        float g0 = 1.0f/(1.0f+expf(-(gv.x+bv.x))), g1 = 1.0f/(1.0f+expf(-(gv.y+bv.y)));
        o1.x = g0*fmaxf(a1.x,0.0f) + (1.0f-g0)*xv.x;
        o1.y = g1*fmaxf(a1.y,0.0f) + (1.0f-g1)*xv.y;
        dst[i1] = o1;
    }
    if (t3) {
        float2 gv = glr[i2], xv = x1r[i2], bv = br[i2];
        float g0 = 1.0f/(1.0f+expf(-(gv.x+bv.x))), g1 = 1.0f/(1.0f+expf(-(gv.y+bv.y)));
        o2.x = g0*fmaxf(a2.x,0.0f) + (1.0f-g0)*xv.x;
        o2.y = g1*fmaxf(a2.y,0.0f) + (1.0f-g1)*xv.y;
        dst[i2] = o2;
    }
    if (hi) {   // fragment-pack o as bf16 hi/lo for the next GEMM's A
        auto pack2 = [&](int k, float2 o) {
            unsigned ux = __float_as_uint(o.x), uy = __float_as_uint(o.y);
            unsigned short hx = (unsigned short)(ux >> 16), hy = (unsigned short)(uy >> 16);
            unsigned short lx = f2bf_rne(o.x - bf2f(hx)), ly = f2bf_rne(o.y - bf2f(hy));
            long off = fragoff(w, k, npk);
            ushort2 hv = {hx, hy}, lv = {lx, ly};
            *(ushort2*)(hi + off) = hv;
            *(ushort2*)(lo + off) = lv;
        };
        pack2(2*lane, o0);
        pack2(128 + 2*lane, o1);
        if (t3) pack2(256 + 2*lane, o2);
        else if (lane < 24) {   // lanes 22,23: zero-fill k = 300,302 (pad)
            long off = fragoff(w, 256 + 2*lane, npk);
            ushort2 z = {0,0};
            *(ushort2*)(hi + off) = z;
            *(ushort2*)(lo + off) = z;
        }
    }
}

// GAT: fused edge score + segment softmax + weighted gather + relu (F=300)
__global__ void k_gat300(const float* __restrict__ x, long ldx,
                         const float* __restrict__ sA, const float* __restrict__ sB,
                         const float* __restrict__ rsc,
                         const int* __restrict__ jp, const int* __restrict__ relp,
                         const int* __restrict__ rowptr, const int* __restrict__ cnt,
                         float* __restrict__ out, long ldo, int n)
{
    int w = (blockIdx.x*blockDim.x + threadIdx.x) >> 6;
    int lane = threadIdx.x & 63;
    if (w >= n) return;
    int beg = rowptr[w], c = cnt[w];
    const int i0 = lane, i1 = lane + 64, i2 = lane + 128;
    const bool t3 = (lane < 22);
    float2 a0 = {0,0}, a1 = {0,0}, a2 = {0,0};
    if (c > 0) {
        float base = sA[w];
        int   jc = 0;
        float sval = -3.4e38f;
        if (lane < c) {
            jc = jp[beg + lane];
            sval = leaky(base + sB[jc] + rsc[relp[beg + lane]]);
        }
        float mx = sval;
        for (int t = 64 + lane; t < c; t += 64)
            mx = fmaxf(mx, leaky(base + sB[jp[beg+t]] + rsc[relp[beg+t]]));
        #pragma unroll
        for (int o = 32; o > 0; o >>= 1) mx = fmaxf(mx, __shfl_xor(mx, o));
        float pexp = (lane < c) ? expf(sval - mx) : 0.0f;
        float ss = pexp;
        for (int t = 64 + lane; t < c; t += 64)
            ss += expf(leaky(base + sB[jp[beg+t]] + rsc[relp[beg+t]]) - mx);
        #pragma unroll
        for (int o = 32; o > 0; o >>= 1) ss += __shfl_xor(ss, o);
        float inv = 1.0f / (ss + 1e-16f);
        int q = 0;
        int cc = (c < 64) ? c : 64;
        for (; q + 4 <= cc; q += 4) {
            float al0 = __shfl(pexp, q)   * inv;
            float al1 = __shfl(pexp, q+1) * inv;
            float al2 = __shfl(pexp, q+2) * inv;
            float al3 = __shfl(pexp, q+3) * inv;
            long  j0 = __shfl(jc, q), j1 = __shfl(jc, q+1);
            long  j2 = __shfl(jc, q+2), j3 = __shfl(jc, q+3);
            const float2* r0 = (const float2*)(x + j0*ldx);
            const float2* r1 = (const float2*)(x + j1*ldx);
            const float2* r2 = (const float2*)(x + j2*ldx);
            const float2* r3 = (const float2*)(x + j3*ldx);
            float2 v;
            v = r0[i0]; a0.x += al0*v.x; a0.y += al0*v.y;
            v = r1[i0]; a0.x += al1*v.x; a0.y += al1*v.y;
            v = r2[i0]; a0.x += al2*v.x; a0.y += al2*v.y;
            v = r3[i0]; a0.x += al3*v.x; a0.y += al3*v.y;
            v = r0[i1]; a1.x += al0*v.x; a1.y += al0*v.y;
            v = r1[i1]; a1.x += al1*v.x; a1.y += al1*v.y;
            v = r2[i1]; a1.x += al2*v.x; a1.y += al2*v.y;
            v = r3[i1]; a1.x += al3*v.x; a1.y += al3*v.y;
            if (t3) {
                v = r0[i2]; a2.x += al0*v.x; a2.y += al0*v.y;
                v = r1[i2]; a2.x += al1*v.x; a2.y += al1*v.y;
                v = r2[i2]; a2.x += al2*v.x; a2.y += al2*v.y;
                v = r3[i2]; a2.x += al3*v.x; a2.y += al3*v.y;
            }
        }
        for (; q < c; ++q) {
            float al; long j0;
            if (q < 64) { al = __shfl(pexp, q) * inv; j0 = __shfl(jc, q); }
            else {
                j0 = jp[beg + q];
                al = expf(leaky(base + sB[(int)j0] + rsc[relp[beg+q]]) - mx) * inv;
            }
            const float2* r0 = (const float2*)(x + j0*ldx);
            float2 v;
            v = r0[i0]; a0.x += al*v.x; a0.y += al*v.y;
            v = r0[i1]; a1.x += al*v.x; a1.y += al*v.y;
            if (t3) { v = r0[i2]; a2.x += al*v.x; a2.y += al*v.y; }
        }
    }
    float2* dst = (float2*)(out + (long)w*ldo);
    a0.x = fmaxf(a0.x, 0.0f); a0.y = fmaxf(a0.y, 0.0f);
    a1.x = fmaxf(a1.x, 0.0f); a1.y = fmaxf(a1.y, 0.0f);
    dst[i0] = a0; dst[i1] = a1;
    if (t3) { a2.x = fmaxf(a2.x, 0.0f); a2.y = fmaxf(a2.y, 0.0f); dst[i2] = a2; }
}

// r2e: fused score = leaky(snode[w] + srel[relp]) + softmax + gather of xr (F=100)
__global__ void k_gather_rel100(const float* __restrict__ xr,
                                const float* __restrict__ snode,
                                const float* __restrict__ srel,
                                const int* __restrict__ relp,
                                const int* __restrict__ rowptr, const int* __restrict__ cnt,
                                float* __restrict__ out, long ldo, int n)
{
    int w = (blockIdx.x*blockDim.x + threadIdx.x) >> 6;
    int lane = threadIdx.x & 63;
    if (w >= n) return;
    int beg = rowptr[w], c = cnt[w];
    const bool t0 = (lane < 50);
    float2 a0 = {0,0};
    if (c > 0) {
        float base = snode[w];
        int   rc = 0;
        float sval = -3.4e38f;
        if (lane < c) {
            rc = relp[beg + lane];
            sval = leaky(base + srel[rc]);
        }
        float mx = sval;
        for (int t = 64 + lane; t < c; t += 64)
            mx = fmaxf(mx, leaky(base + srel[relp[beg+t]]));
        #pragma unroll
        for (int o = 32; o > 0; o >>= 1) mx = fmaxf(mx, __shfl_xor(mx, o));
        float pexp = (lane < c) ? expf(sval - mx) : 0.0f;
        float ss = pexp;
        for (int t = 64 + lane; t < c; t += 64)
            ss += expf(leaky(base + srel[relp[beg+t]]) - mx);
        #pragma unroll
        for (int o = 32; o > 0; o >>= 1) ss += __shfl_xor(ss, o);
        float inv = 1.0f / (ss + 1e-16f);
        int q = 0;
        int cc = (c < 64) ? c : 64;
        for (; q + 4 <= cc; q += 4) {
            float al0 = __shfl(pexp, q)   * inv;
            float al1 = __shfl(pexp, q+1) * inv;
            float al2 = __shfl(pexp, q+2) * inv;
            float al3 = __shfl(pexp, q+3) * inv;
            long r0i = __shfl(rc, q), r1i = __shfl(rc, q+1);
            long r2i = __shfl(rc, q+2), r3i = __shfl(rc, q+3);
            if (t0) {
                float2 v;
                v = ((const float2*)(xr + r0i*100))[lane]; a0.x += al0*v.x; a0.y += al0*v.y;
                v = ((const float2*)(xr + r1i*100))[lane]; a0.x += al1*v.x; a0.y += al1*v.y;
                v = ((const float2*)(xr + r2i*100))[lane]; a0.x += al2*v.x; a0.y += al2*v.y;
                v = ((const float2*)(xr + r3i*100))[lane]; a0.x += al3*v.x; a0.y += al3*v.y;
            }
        }
        for (; q < c; ++q) {
            float al; long r0i;
            if (q < 64) { al = __shfl(pexp, q) * inv; r0i = __shfl(rc, q); }
            else {
                r0i = relp[beg + q];
                al = expf(leaky(base + srel[(int)r0i]) - mx) * inv;
            }
            if (t0) {
                float2 v = ((const float2*)(xr + r0i*100))[lane];
                a0.x += al*v.x; a0.y += al*v.y;
            }
        }
    }
    if (t0) ((float2*)(out + (long)w*ldo))[lane] = a0;
}

// ---------- highway combine (small R x RH path) ----------
__global__ void k_highway(const float* __restrict__ x1, long ld1,
                          const float* __restrict__ gl, long ldg,
                          const float* __restrict__ x2, long ld2,
                          const float* __restrict__ bias,
                          float* __restrict__ out, long ldo,
                          long rows, int F, int relu_x2)
{
    long idx = (long)blockIdx.x*blockDim.x + threadIdx.x;
    if (idx >= rows * (long)F) return;
    long r = idx / F; int c = (int)(idx % F);
    float g = 1.0f / (1.0f + expf(-(gl[r*ldg+c] + bias[c])));
    float v2 = x2[r*ld2+c]; if (relu_x2) v2 = fmaxf(v2, 0.0f);
    float v1 = x1[r*ld1+c];
    out[r*ldo+c] = g*v2 + (1.0f-g)*v1;
}

// ---------- segment softmax building blocks (small l_gat path only) ----------
__global__ void k_segmax(const float* __restrict__ ev, const int* __restrict__ idx,
                         unsigned* __restrict__ m, int E) {
    int e = blockIdx.x*blockDim.x + threadIdx.x;
    if (e < E) atomicMax(&m[idx[e]], f2mono(ev[e]));
}
__global__ void k_segsumexp(const float* __restrict__ ev, const int* __restrict__ idx,
                            const unsigned* __restrict__ m, float* __restrict__ s, int E) {
    int e = blockIdx.x*blockDim.x + threadIdx.x;
    if (e < E) atomicAdd(&s[idx[e]], expf(ev[e] - mono2f(m[idx[e]])));
}
__global__ void k_lgat_vsum(const float* __restrict__ val,
                            const int* __restrict__ jj, const int* __restrict__ ii,
                            const unsigned* __restrict__ mi, const float* __restrict__ si,
                            const unsigned* __restrict__ mj, const float* __restrict__ sj,
                            float* __restrict__ vsum, int E)
{
    int e = blockIdx.x*blockDim.x + threadIdx.x;
    if (e >= E) return;
    float v = val[e];
    int i = ii[e], j = jj[e];
    float pi = expf(v - mono2f(mi[i])) / (si[i] + 1e-16f);
    float pj = expf(v - mono2f(mj[j])) / (sj[j] + 1e-16f);
    vsum[e] = pi + pj;
}
__global__ void k_edge_agg(const float* __restrict__ ev,
                           const unsigned* __restrict__ m, const float* __restrict__ s,
                           const int* __restrict__ ka, const int* __restrict__ ko,
                           const int* __restrict__ ks,
                           const float* __restrict__ x, long ldx,
                           float* __restrict__ out, long ldo,
                           int E, int F)
{
    int w = (blockIdx.x*blockDim.x + threadIdx.x) >> 6;
    int lane = threadIdx.x & 63;
    if (w >= E) return;
    int a = ka[w];
    float alpha = expf(ev[w] - mono2f(m[a])) / (s[a] + 1e-16f);
    const float4* src = (const float4*)(x + (long)ks[w]*ldx);
    float* dst = out + (long)ko[w]*ldo;
    int nf4 = F >> 2;
    for (int f = lane; f < nf4; f += WAVE) {
        float4 v = src[f];
        atomicAdd(&dst[f*4+0], alpha*v.x);
        atomicAdd(&dst[f*4+1], alpha*v.y);
        atomicAdd(&dst[f*4+2], alpha*v.z);
        atomicAdd(&dst[f*4+3], alpha*v.w);
    }
}
__global__ void k_relu2d(float* __restrict__ p, long rows, int cols, long ld) {
    long idx = (long)blockIdx.x*blockDim.x + threadIdx.x;
    if (idx >= rows*(long)cols) return;
    long r = idx / cols; int c = (int)(idx % cols);
    float v = p[r*ld+c];
    p[r*ld+c] = fmaxf(v, 0.0f);
}

// ---------- row dots ----------
__global__ void k_rowdot2(const float* __restrict__ x, long ldx, int rows, int K,
                          const float* __restrict__ a, const float* __restrict__ b,
                          float* __restrict__ oa, float* __restrict__ ob)
{
    int w = (blockIdx.x*blockDim.x + threadIdx.x) >> 6;
    int lane = threadIdx.x & 63;
    if (w >= rows) return;
    const float* xr = x + (long)w*ldx;
    float sa = 0.0f, sb = 0.0f;
    for (int k = lane; k < K; k += WAVE) {
        float v = xr[k];
        sa += v * a[k];
        if (b) sb += v * b[k];
    }
    #pragma unroll
    for (int off = 32; off > 0; off >>= 1) {
        sa += __shfl_down(sa, off);
        if (b) sb += __shfl_down(sb, off);
    }
    if (lane == 0) { oa[w] = sa; if (ob) ob[w] = sb; }
}

// ---------- relscore[r] = merge[r]·ar[0:RH] + tri[r]·ar[RH:2RH] ----------
__global__ void k_relscore(const float* __restrict__ mg, const float* __restrict__ tr,
                           const float* __restrict__ ar, float* __restrict__ out, int R, int RH)
{
    int w = (blockIdx.x*blockDim.x + threadIdx.x) >> 6;
    int lane = threadIdx.x & 63;
    if (w >= R) return;
    float s = 0.0f;
    for (int k = lane; k < RH; k += WAVE)
        s += mg[(long)w*RH+k]*ar[k] + tr[(long)w*RH+k]*ar[RH+k];
    #pragma unroll
    for (int off = 32; off > 0; off >>= 1) s += __shfl_down(s, off);
    if (lane == 0) out[w] = s;
}

extern "C" void kernel_launch(void* const* d_in, const int* in_sizes, int n_in,
                              void* d_out, int out_size, void* d_ws, size_t ws_size,
                              hipStream_t stream)
{
    const float* x_e   = (const float*)d_in[0];
    const float* mval  = (const float*)d_in[1];
    const float* tval  = (const float*)d_in[2];
    const float* g1w   = (const float*)d_in[3];
    const float* h1w   = (const float*)d_in[4];
    const float* h1b   = (const float*)d_in[5];
    const float* g2w   = (const float*)d_in[6];
    const float* h2w   = (const float*)d_in[7];
    const float* h2b   = (const float*)d_in[8];
    const float* remb1 = (const float*)d_in[9];
    const float* remb2 = (const float*)d_in[10];
    const float* hrw   = (const float*)d_in[11];
    const float* hrb   = (const float*)d_in[12];
    const float* gat_ai= (const float*)d_in[13];
    const float* gat_aj= (const float*)d_in[14];
    const float* gat_ar= (const float*)d_in[15];
    const float* g2e_ah= (const float*)d_in[16];
    const float* g2e_at= (const float*)d_in[17];
    const float* g2e_ar= (const float*)d_in[18];
    const int* edge_index     = (const int*)d_in[19];
    const int* rel            = (const int*)d_in[20];
    const int* edge_index_all = (const int*)d_in[21];
    const int* rel_all        = (const int*)d_in[22];
    const int* lg_merge       = (const int*)d_in[23];
    const int* lg_tri         = (const int*)d_in[24];

    const int F    = 300;
    const int RH   = 100;
    const int Kp   = 304;                  // padded K
    const int npk  = Kp / 16;              // 19 k-steps
    const int N    = in_sizes[0] / F;      // 100000 (multiple of 32)
    const int E    = in_sizes[20];         // 400000
    const int EA   = in_sizes[22];         // 800000
    const int LGE  = in_sizes[1];          // 60000
    const int R    = in_sizes[9] / RH;     // 2000
    const long OUTC = 800;
    const int Mpad = CDIV(N, 128) * 128;   // 100096
    const int NB   = 640;                  // fused B rows: W_g @0..299, W_h @320..619
    const long LDC = 640;

    const int* jA = edge_index_all;
    const int* iA = edge_index_all + EA;
    const int* hE = edge_index;
    const int* tE = edge_index + E;
    const int* jM = lg_merge;  const int* iM = lg_merge + LGE;
    const int* jT = lg_tri;    const int* iT = lg_tri  + LGE;

    float* ws = (float*)d_ws;
    size_t off = 0;
    auto alloc = [&](size_t n) { float* p = ws + off; off += (n + 3) & ~(size_t)3; return p; };
    float*    Ascr = alloc((size_t)N*NB);                      // fused GEMM output [N,640]
    unsigned short* Axh = (unsigned short*)alloc((size_t)Mpad*Kp/2);  // A packed hi
    unsigned short* Axl = (unsigned short*)alloc((size_t)Mpad*Kp/2);  // A packed lo
    unsigned short* Wh[2]; unsigned short* Wl[2];
    for (int i = 0; i < 2; ++i) {
        Wh[i] = (unsigned short*)alloc((size_t)NB*Kp/2);
        Wl[i] = (unsigned short*)alloc((size_t)NB*Kp/2);
    }
    float*    dinv = alloc(N);
    float*    sA_  = alloc(N);
    float*    sB_  = alloc(N);
    float*    mrg  = alloc((size_t)R*RH);
    float*    tri  = alloc((size_t)R*RH);
    float*    xr   = alloc((size_t)R*RH);
    float*    xrg  = alloc((size_t)R*RH);
    unsigned* lmi  = (unsigned*)alloc(R);  float* lsi = alloc(R);
    unsigned* lmj  = (unsigned*)alloc(R);  float* lsj = alloc(R);
    unsigned* lm2  = (unsigned*)alloc(R);  float* ls2 = alloc(R);
    float*    vsum = alloc(LGE);
    float*    rsc  = alloc(R);
    float*    srel = alloc(R);
    int*   bsum    = (int*)alloc(1024);
    int*   cursor  = (int*)alloc(N);
    int*   rowptrA = (int*)alloc(N); int* cntA = (int*)alloc(N); int* permA = (int*)alloc(EA);
    int*   rowptrH = (int*)alloc(N); int* cntH = (int*)alloc(N); int* permH = (int*)alloc(E);
    int*   rowptrT = (int*)alloc(N); int* cntT = (int*)alloc(N); int* permT = (int*)alloc(E);
    int*   jpA     = (int*)alloc(EA);
    float* nmA     = alloc(EA);
    int*   relpA   = (int*)alloc(EA);
    int*   relpH   = (int*)alloc(E);
    int*   relpT   = (int*)alloc(E);

    float* out = (float*)d_out;              // [N, 800]

    const int  nb = CDIV(N, 256);
    dim3 gemmGrid(5, CDIV(N, 128));          // 5 col-blocks x 782 row-blocks
    const int gatherGrid = CDIV(N, 4);
    const int cvtBigGrid = CDIV((long)N * (Kp/4), 256);
    const int cvtWGrid   = CDIV(300 * (Kp/4), 256);

    auto build_csr = [&](const int* key, int E_, int* rowptr, int* cnt, int* perm) {
        hipMemsetAsync(cnt, 0, (size_t)N*4, stream);
        k_hist<<<CDIV(E_,256),256,0,stream>>>(key, cnt, E_);
        k_scan1<<<nb,256,0,stream>>>(cnt, rowptr, bsum, N);
        k_scan2<<<1,1024,0,stream>>>(bsum, nb);
        k_scan3<<<nb,256,0,stream>>>(rowptr, bsum, N);
        hipMemsetAsync(cursor, 0, (size_t)N*4, stream);
        k_fill<<<CDIV(E_,256),256,0,stream>>>(key, rowptr, cursor, perm, E_);
    };

    // ===== zero pads, then fragment-pack converts (fused W: g @0, h @320) =====
    for (int i = 0; i < 2; ++i) {
        hipMemsetAsync(Wh[i], 0, (size_t)NB*Kp*2, stream);
        hipMemsetAsync(Wl[i], 0, (size_t)NB*Kp*2, stream);
    }
    hipMemsetAsync(Axh + (size_t)N*Kp, 0, (size_t)(Mpad-N)*Kp*2, stream);
    hipMemsetAsync(Axl + (size_t)N*Kp, 0, (size_t)(Mpad-N)*Kp*2, stream);
    k_cvt_pack<<<cvtWGrid,256,0,stream>>>(g1w, 300, 300, 300, npk, 0,   Wh[0], Wl[0]);
    k_cvt_pack<<<cvtWGrid,256,0,stream>>>(h1w, 300, 300, 300, npk, 320, Wh[0], Wl[0]);
    k_cvt_pack<<<cvtWGrid,256,0,stream>>>(g2w, 300, 300, 300, npk, 0,   Wh[1], Wl[1]);
    k_cvt_pack<<<cvtWGrid,256,0,stream>>>(h2w, 300, 300, 300, npk, 320, Wh[1], Wl[1]);
    k_cvt_pack<<<cvtBigGrid,256,0,stream>>>(x_e, 300, N, 300, npk, 0, Axh, Axl);

    // ===== CSRs + pre-permutes =====
    build_csr(iA, EA, rowptrA, cntA, permA);
    build_csr(hE, E,  rowptrH, cntH, permH);
    build_csr(tE, E,  rowptrT, cntT, permT);
    k_dinv_cnt<<<CDIV(N,256),256,0,stream>>>(cntA, dinv, N);
    k_prep_gcn<<<CDIV(EA,256),256,0,stream>>>(permA, jA, iA, dinv, jpA, nmA, EA);
    k_permute_mod<<<CDIV(EA,256),256,0,stream>>>(rel_all, permA, relpA, EA, R);
    k_permute_i32<<<CDIV(E,256),256,0,stream>>>(rel, permH, relpH, E);
    k_permute_i32<<<CDIV(E,256),256,0,stream>>>(rel, permT, relpT, E);

    // ===== GCN layer 1: fused double-GEMM + fused gather/highway/pack =====
    k_gemm_frag<<<gemmGrid,256,0,stream>>>(Axh, Axl, Wh[0], Wl[0], Ascr, LDC, N, 620, npk);
    k_gather_hw<<<gatherGrid,256,0,stream>>>(Ascr, LDC, Ascr+320, x_e, 300, h1b,
                                             jpA, nmA, rowptrA, cntA,
                                             out, OUTC, Axh, Axl, npk, N);

    // ===== GCN layer 2 =====
    k_gemm_frag<<<gemmGrid,256,0,stream>>>(Axh, Axl, Wh[1], Wl[1], Ascr, LDC, N, 620, npk);
    k_gather_hw<<<gatherGrid,256,0,stream>>>(Ascr, LDC, Ascr+320, out, OUTC, h2b,
                                             jpA, nmA, rowptrA, cntA,
                                             out, OUTC, (unsigned short*)nullptr,
                                             (unsigned short*)nullptr, npk, N);

    // ===== l_gat on the two line graphs (small; atomic path) =====
    auto lgat = [&](const float* xrel, const int* jjE, const int* iiE, const float* val, float* obuf) {
        hipMemsetAsync(lmi, 0, R*4, stream); hipMemsetAsync(lsi, 0, R*4, stream);
        hipMemsetAsync(lmj, 0, R*4, stream); hipMemsetAsync(lsj, 0, R*4, stream);
        hipMemsetAsync(lm2, 0, R*4, stream); hipMemsetAsync(ls2, 0, R*4, stream);
        hipMemsetAsync(obuf, 0, (size_t)R*RH*4, stream);
        k_segmax   <<<CDIV(LGE,256),256,0,stream>>>(val, iiE, lmi, LGE);
        k_segmax   <<<CDIV(LGE,256),256,0,stream>>>(val, jjE, lmj, LGE);
        k_segsumexp<<<CDIV(LGE,256),256,0,stream>>>(val, iiE, lmi, lsi, LGE);
        k_segsumexp<<<CDIV(LGE,256),256,0,stream>>>(val, jjE, lmj, lsj, LGE);
        k_lgat_vsum<<<CDIV(LGE,256),256,0,stream>>>(val, jjE, iiE, lmi, lsi, lmj, lsj, vsum, LGE);
        k_segmax   <<<CDIV(LGE,256),256,0,stream>>>(vsum, jjE, lm2, LGE);
        k_segsumexp<<<CDIV(LGE,256),256,0,stream>>>(vsum, jjE, lm2, ls2, LGE);
        k_edge_agg <<<(int)CDIV((long)LGE*64,256),256,0,stream>>>(vsum, lm2, ls2, jjE, iiE, jjE,
                                                                  xrel, RH, obuf, RH, LGE, RH);
        k_relu2d   <<<CDIV((long)R*RH,256),256,0,stream>>>(obuf, R, RH, RH);
    };
    lgat(remb1, jM, iM, mval, mrg);
    lgat(remb2, jT, iT, tval, tri);

    // ===== x_r = highway(mrg, tri, hrw, hrb) =====
    dim3 gridR(CDIV(RH,GBN), CDIV(R,GBM));
    k_gemm<<<gridR,256,0,stream>>>(mrg, RH, hrw, RH, xrg, RH, R, RH, RH);
    k_highway<<<CDIV((long)R*RH,256),256,0,stream>>>(mrg, RH, xrg, RH, tri, RH, hrb, xr, RH, R, RH, 0);

    // relscore[r] = rel_cat[r]·gat_ar
    k_relscore<<<CDIV((long)R*64,256),256,0,stream>>>(mrg, tri, gat_ar, rsc, R, RH);

    // ===== GAT over edge_index_all -> out cols 300..599 (fully fused) =====
    k_rowdot2<<<CDIV((long)N*64,256),256,0,stream>>>(out, OUTC, N, F, gat_ai, gat_aj, sA_, sB_);
    k_gat300<<<gatherGrid,256,0,stream>>>(out, OUTC, sA_, sB_, rsc, jpA, relpA,
                                          rowptrA, cntA, out+300, OUTC, N);

    // ===== gat_r_to_e over edge_index -> out cols 600..799 (fully fused) =====
    k_rowdot2<<<CDIV((long)N*64,256),256,0,stream>>>(out, OUTC, N, 2*F, g2e_ah, g2e_at, sA_, sB_);
    k_rowdot2<<<CDIV((long)R*64,256),256,0,stream>>>(xr, RH, R, RH, g2e_ar, (const float*)nullptr,
                                                     srel, (float*)nullptr);
    k_gather_rel100<<<gatherGrid,256,0,stream>>>(xr, sA_, srel, relpH, rowptrH, cntH,
                                                 out+600, OUTC, N);
    k_gather_rel100<<<gatherGrid,256,0,stream>>>(xr, sB_, srel, relpT, rowptrT, cntT,
                                                 out+700, OUTC, N);
}

// Round 9
// 1651.122 us; speedup vs baseline: 1.4941x; 1.1999x over previous
//
#include <hip/hip_runtime.h>

#define WAVE 64
#define CDIV(a,b) (((a)+(b)-1)/(b))

typedef float f32x16 __attribute__((ext_vector_type(16)));
typedef unsigned short u16x8 __attribute__((ext_vector_type(8)));

// ---------- bf16 helpers: hi = truncate, lo = rne(residual) ----------
__device__ __forceinline__ unsigned short f2bf_rne(float f) {
    unsigned u = __float_as_uint(f);
    unsigned r = (u + 0x7FFFu + ((u >> 16) & 1u)) >> 16;
    return (unsigned short)r;
}
__device__ __forceinline__ float bf2f(unsigned short h) {
    return __uint_as_float(((unsigned)h) << 16);
}
__device__ __forceinline__ float2 bfp2f(ushort2 u) {
    float2 r; r.x = bf2f(u.x); r.y = bf2f(u.y); return r;
}

#define MFMA32(acc, a, b) \
    asm volatile("v_mfma_f32_32x32x16_bf16 %0, %1, %2, %0" : "+v"(acc) : "v"(a), "v"(b))

// ---------- monotonic float<->uint encoding for atomicMax on floats ----------
__device__ __forceinline__ unsigned f2mono(float f) {
    unsigned u = __float_as_uint(f);
    return (u & 0x80000000u) ? ~u : (u | 0x80000000u);
}
__device__ __forceinline__ float mono2f(unsigned u) {
    return (u & 0x80000000u) ? __uint_as_float(u & 0x7fffffffu) : __uint_as_float(~u);
}
__device__ __forceinline__ float leaky(float v) { return (v > 0.0f) ? v : 0.01f*v; }

// fragment-pack offset: matrix row r, col k -> packed short index.
__device__ __forceinline__ long fragoff(long r, int k, int npk) {
    return ((r >> 5) * (long)npk + (k >> 4)) * 512
         + (((k >> 3) & 1) << 8) + ((r & 31) << 3) + (k & 7);
}

// =========================================================================
// k_cvt_pack: f32 [rows][K] (stride ld) -> fragment-packed bf16 hi/lo at
// packed-row offset roff. k-pad (K..npk*16) zeroed.
// =========================================================================
__global__ void k_cvt_pack(const float* __restrict__ src, long ld, int rows, int K, int npk,
                           int roff,
                           unsigned short* __restrict__ hi, unsigned short* __restrict__ lo)
{
    int nc4 = npk << 2;
    long idx = (long)blockIdx.x*blockDim.x + threadIdx.x;
    if (idx >= (long)rows * nc4) return;
    long r = idx / nc4; int k = (int)(idx % nc4) << 2;
    float4 v = {0.0f, 0.0f, 0.0f, 0.0f};
    if (k + 4 <= K) v = *(const float4*)(src + r*ld + k);
    float vv[4] = {v.x, v.y, v.z, v.w};
    ushort4 h, l;
    unsigned short hh[4], ll[4];
    #pragma unroll
    for (int i = 0; i < 4; ++i) {
        unsigned u = __float_as_uint(vv[i]);
        hh[i] = (unsigned short)(u >> 16);
        ll[i] = f2bf_rne(vv[i] - bf2f(hh[i]));
    }
    h.x = hh[0]; h.y = hh[1]; h.z = hh[2]; h.w = hh[3];
    l.x = ll[0]; l.y = ll[1]; l.z = ll[2]; l.w = ll[3];
    long off = fragoff(r + roff, k, npk);
    *(ushort4*)(hi + off) = h;
    *(ushort4*)(lo + off) = l;
}

// =========================================================================
// k_gemm_frag: C[M,N'] (bf16, row-major) = A * B^T on fragment-packed
// bf16 hi/lo. NO LDS, NO barriers. Block 256 thr = 4 waves; wave = 32 rows
// x 128 cols. bf16x3: AhBh + AlBh + AhBl (~fp32 accuracy, bf16-rounded out).
// =========================================================================
__global__ __launch_bounds__(256, 3)
void k_gemm_frag(const unsigned short* __restrict__ Ahi, const unsigned short* __restrict__ Alo,
                 const unsigned short* __restrict__ Bhi, const unsigned short* __restrict__ Blo,
                 unsigned short* __restrict__ C, long ldc, int M, int N, int nk)
{
    const int lane = threadIdx.x & 63;
    const int wid  = threadIdx.x >> 6;
    const int col0 = blockIdx.x * 128;
    const int row0 = blockIdx.y * 128 + wid * 32;

    const long cs = (long)nk * 512;                 // tile-row stride (shorts)
    const unsigned short* pAh = Ahi + (long)(row0 >> 5) * cs + lane * 8;
    const unsigned short* pAl = Alo + (long)(row0 >> 5) * cs + lane * 8;
    const unsigned short* pBh = Bhi + (long)(col0 >> 5) * cs + lane * 8;
    const unsigned short* pBl = Blo + (long)(col0 >> 5) * cs + lane * 8;

    f32x16 acc[4];
    #pragma unroll
    for (int c = 0; c < 4; ++c) acc[c] = (f32x16)0.0f;

    u16x8 pah, pal, pb0, pb1, pb2, pb3, pl0, pl1, pl2, pl3;
    u16x8 qah, qal, qb0, qb1, qb2, qb3, ql0, ql1, ql2, ql3;

    #define LOADP(t_) { long o = (long)(t_)*512;                                   \
        pah = *(const u16x8*)(pAh + o);        pal = *(const u16x8*)(pAl + o);     \
        pb0 = *(const u16x8*)(pBh + o);        pl0 = *(const u16x8*)(pBl + o);     \
        pb1 = *(const u16x8*)(pBh + cs + o);   pl1 = *(const u16x8*)(pBl + cs + o);\
        pb2 = *(const u16x8*)(pBh + 2*cs + o); pl2 = *(const u16x8*)(pBl + 2*cs + o);\
        pb3 = *(const u16x8*)(pBh + 3*cs + o); pl3 = *(const u16x8*)(pBl + 3*cs + o); }
    #define LOADQ(t_) { long o = (long)(t_)*512;                                   \
        qah = *(const u16x8*)(pAh + o);        qal = *(const u16x8*)(pAl + o);     \
        qb0 = *(const u16x8*)(pBh + o);        ql0 = *(const u16x8*)(pBl + o);     \
        qb1 = *(const u16x8*)(pBh + cs + o);   ql1 = *(const u16x8*)(pBl + cs + o);\
        qb2 = *(const u16x8*)(pBh + 2*cs + o); ql2 = *(const u16x8*)(pBl + 2*cs + o);\
        qb3 = *(const u16x8*)(pBh + 3*cs + o); ql3 = *(const u16x8*)(pBl + 3*cs + o); }
    #define STEPP {                                                                 \
        MFMA32(acc[0], pah, pb0); MFMA32(acc[1], pah, pb1);                         \
        MFMA32(acc[2], pah, pb2); MFMA32(acc[3], pah, pb3);                         \
        MFMA32(acc[0], pal, pb0); MFMA32(acc[1], pal, pb1);                         \
        MFMA32(acc[2], pal, pb2); MFMA32(acc[3], pal, pb3);                         \
        MFMA32(acc[0], pah, pl0); MFMA32(acc[1], pah, pl1);                         \
        MFMA32(acc[2], pah, pl2); MFMA32(acc[3], pah, pl3); }
    #define STEPQ {                                                                 \
        MFMA32(acc[0], qah, qb0); MFMA32(acc[1], qah, qb1);                         \
        MFMA32(acc[2], qah, qb2); MFMA32(acc[3], qah, qb3);                         \
        MFMA32(acc[0], qal, qb0); MFMA32(acc[1], qal, qb1);                         \
        MFMA32(acc[2], qal, qb2); MFMA32(acc[3], qal, qb3);                         \
        MFMA32(acc[0], qah, ql0); MFMA32(acc[1], qah, ql1);                         \
        MFMA32(acc[2], qah, ql2); MFMA32(acc[3], qah, ql3); }

    LOADP(0);
    int t = 0;
    for (;;) {
        bool m1 = (t + 1 < nk);
        if (m1) LOADQ(t + 1);
        STEPP;
        if (!m1) break;
        bool m2 = (t + 2 < nk);
        if (m2) LOADP(t + 2);
        STEPQ;
        if (!m2) break;
        t += 2;
    }
    #undef LOADP
    #undef LOADQ
    #undef STEPP
    #undef STEPQ

    const int crow0 = row0 + 4*(lane >> 5);
    const int ccol0 = col0 + (lane & 31);
    #pragma unroll
    for (int c = 0; c < 4; ++c) {
        int col = ccol0 + c*32;
        if (col >= N) continue;
        #pragma unroll
        for (int reg = 0; reg < 16; ++reg) {
            int row = crow0 + (reg & 3) + 8*(reg >> 2);
            if (row < M) C[(long)row*ldc + col] = f2bf_rne(acc[c][reg]);
        }
    }
}

// ---------- small f32 GEMM (tiny R x RH highway gate) ----------
#define GBM 64
#define GBN 64
#define GBK 16
__global__ __launch_bounds__(256)
void k_gemm(const float* __restrict__ A, long lda,
            const float* __restrict__ B, long ldb,
            float* __restrict__ C, long ldc,
            int M, int N, int K)
{
    __shared__ float As[GBK][GBM + 4];
    __shared__ float Bs[GBK][GBN + 4];
    const int tid = threadIdx.x;
    const int tx = tid & 15, ty = tid >> 4;
    const int row0 = blockIdx.y * GBM, col0 = blockIdx.x * GBN;
    float acc[4][4] = {};
    for (int kt = 0; kt < K; kt += GBK) {
        #pragma unroll
        for (int p = 0; p < 4; ++p) {
            int mn = (tid >> 4) + p * 16;
            int k  = tid & 15;
            int gk = kt + k;
            int gr = row0 + mn;
            As[k][mn] = (gr < M && gk < K) ? A[(long)gr * lda + gk] : 0.0f;
            int gc = col0 + mn;
            Bs[k][mn] = (gc < N && gk < K) ? B[(long)gc * ldb + gk] : 0.0f;
        }
        __syncthreads();
        #pragma unroll
        for (int kk = 0; kk < GBK; ++kk) {
            float a0 = As[kk][ty*4+0], a1 = As[kk][ty*4+1];
            float a2 = As[kk][ty*4+2], a3 = As[kk][ty*4+3];
            float b0 = Bs[kk][tx*4+0], b1 = Bs[kk][tx*4+1];
            float b2 = Bs[kk][tx*4+2], b3 = Bs[kk][tx*4+3];
            acc[0][0] += a0*b0; acc[0][1] += a0*b1; acc[0][2] += a0*b2; acc[0][3] += a0*b3;
            acc[1][0] += a1*b0; acc[1][1] += a1*b1; acc[1][2] += a1*b2; acc[1][3] += a1*b3;
            acc[2][0] += a2*b0; acc[2][1] += a2*b1; acc[2][2] += a2*b2; acc[2][3] += a2*b3;
            acc[3][0] += a3*b0; acc[3][1] += a3*b1; acc[3][2] += a3*b2; acc[3][3] += a3*b3;
        }
        __syncthreads();
    }
    #pragma unroll
    for (int i2 = 0; i2 < 4; ++i2)
        #pragma unroll
        for (int j2 = 0; j2 < 4; ++j2) {
            int r = row0 + ty*4 + i2, c = col0 + tx*4 + j2;
            if (r < M && c < N) C[(long)r*ldc + c] = acc[i2][j2];
        }
}

// ================= CSR build: histogram -> scan -> fill =================
__global__ void k_hist(const int* __restrict__ key, int* __restrict__ cnt, int E) {
    int e = blockIdx.x*blockDim.x + threadIdx.x;
    if (e < E) atomicAdd(&cnt[key[e]], 1);
}
__global__ void k_scan1(const int* __restrict__ in, int* __restrict__ out,
                        int* __restrict__ bsum, int n) {
    __shared__ int sh[256];
    int gid = blockIdx.x*256 + threadIdx.x;
    int v = (gid < n) ? in[gid] : 0;
    sh[threadIdx.x] = v; __syncthreads();
    for (int o = 1; o < 256; o <<= 1) {
        int t = (threadIdx.x >= o) ? sh[threadIdx.x - o] : 0;
        __syncthreads();
        sh[threadIdx.x] += t;
        __syncthreads();
    }
    if (gid < n) out[gid] = sh[threadIdx.x] - v;      // exclusive
    if (threadIdx.x == 255) bsum[blockIdx.x] = sh[255];
}
__global__ void k_scan2(int* __restrict__ bsum, int nb) {   // single block, nb <= 1024
    __shared__ int sh[1024];
    int v = (threadIdx.x < nb) ? bsum[threadIdx.x] : 0;
    sh[threadIdx.x] = v; __syncthreads();
    for (int o = 1; o < 1024; o <<= 1) {
        int t = (threadIdx.x >= o) ? sh[threadIdx.x - o] : 0;
        __syncthreads();
        sh[threadIdx.x] += t;
        __syncthreads();
    }
    if (threadIdx.x < nb) bsum[threadIdx.x] = sh[threadIdx.x] - v;  // exclusive
}
__global__ void k_scan3(int* __restrict__ out, const int* __restrict__ bsum, int n) {
    int gid = blockIdx.x*256 + threadIdx.x;
    if (gid < n) out[gid] += bsum[blockIdx.x];
}
__global__ void k_fill(const int* __restrict__ key, const int* __restrict__ rowptr,
                       int* __restrict__ cursor, int* __restrict__ perm, int E) {
    int e = blockIdx.x*blockDim.x + threadIdx.x;
    if (e >= E) return;
    int k = key[e];
    int p = rowptr[k] + atomicAdd(&cursor[k], 1);
    perm[p] = e;
}
__global__ void k_dinv_cnt(const int* __restrict__ cnt, float* __restrict__ dinv, int n) {
    int i = blockIdx.x*blockDim.x + threadIdx.x;
    if (i < n) { int c = cnt[i]; dinv[i] = (c > 0) ? rsqrtf((float)c) : 0.0f; }
}

// ---------- CSR-order pre-permutation ----------
__global__ void k_prep_gcn(const int* __restrict__ perm, const int* __restrict__ jA,
                           const int* __restrict__ iA, const float* __restrict__ dinv,
                           int* __restrict__ jp, float* __restrict__ nm, int E) {
    int p = blockIdx.x*blockDim.x + threadIdx.x;
    if (p >= E) return;
    int e = perm[p];
    int j = jA[e];
    jp[p] = j;
    nm[p] = dinv[iA[e]] * dinv[j];
}
__global__ void k_permute_i32(const int* __restrict__ src, const int* __restrict__ perm,
                              int* __restrict__ dst, int E) {
    int p = blockIdx.x*blockDim.x + threadIdx.x;
    if (p < E) dst[p] = src[perm[p]];
}
__global__ void k_permute_mod(const int* __restrict__ src, const int* __restrict__ perm,
                              int* __restrict__ dst, int E, int mod) {
    int p = blockIdx.x*blockDim.x + threadIdx.x;
    if (p < E) dst[p] = src[perm[p]] % mod;
}

// =========================================================================
// k_gather_hw: fused GCN gather (bf16 src) + relu + highway + extras.
// Wave per node w:
//   acc = sum nm[p] * bf2f(xg[jp[p], 0..299])   (xg bf16, ld ldx shorts)
//   g = sigmoid(bf2f(gl[w]) + bias); o = g*relu(acc) + (1-g)*x1[w]
//   out[w,0..299] = o (f32)
//   if (hi):  fragment-pack o as bf16 hi/lo (next GEMM's A)     [layer 1]
//   if (xbf): row-major bf16 copy of o (stride 304)             [layer 2]
//   if (sa):  sa[w]=o·ai, sb[w]=o·aj (GAT score dots)           [layer 2]
// =========================================================================
__global__ void k_gather_hw(const unsigned short* __restrict__ xg, long ldx,
                            const unsigned short* __restrict__ gl,
                            const float* __restrict__ x1, long ld1,
                            const float* __restrict__ bias,
                            const int* __restrict__ jp, const float* __restrict__ nm,
                            const int* __restrict__ rowptr, const int* __restrict__ cnt,
                            float* __restrict__ out, long ldo,
                            unsigned short* __restrict__ hi, unsigned short* __restrict__ lo,
                            unsigned short* __restrict__ xbf,
                            const float* __restrict__ ai, const float* __restrict__ aj,
                            float* __restrict__ sa, float* __restrict__ sb,
                            int npk, int n)
{
    int w = (blockIdx.x*blockDim.x + threadIdx.x) >> 6;
    int lane = threadIdx.x & 63;
    if (w >= n) return;
    int beg = rowptr[w], end = beg + cnt[w];
    const int i0 = lane, i1 = lane + 64, i2 = lane + 128;
    const bool t3 = (lane < 22);
    float2 a0 = {0,0}, a1 = {0,0}, a2 = {0,0};
    int e = beg;
    for (; e + 4 <= end; e += 4) {
        const ushort2* r0 = (const ushort2*)(xg + (long)jp[e]  *ldx);
        const ushort2* r1 = (const ushort2*)(xg + (long)jp[e+1]*ldx);
        const ushort2* r2 = (const ushort2*)(xg + (long)jp[e+2]*ldx);
        const ushort2* r3 = (const ushort2*)(xg + (long)jp[e+3]*ldx);
        float w0 = nm[e], w1 = nm[e+1], w2 = nm[e+2], w3 = nm[e+3];
        float2 v;
        v = bfp2f(r0[i0]); a0.x += w0*v.x; a0.y += w0*v.y;
        v = bfp2f(r1[i0]); a0.x += w1*v.x; a0.y += w1*v.y;
        v = bfp2f(r2[i0]); a0.x += w2*v.x; a0.y += w2*v.y;
        v = bfp2f(r3[i0]); a0.x += w3*v.x; a0.y += w3*v.y;
        v = bfp2f(r0[i1]); a1.x += w0*v.x; a1.y += w0*v.y;
        v = bfp2f(r1[i1]); a1.x += w1*v.x; a1.y += w1*v.y;
        v = bfp2f(r2[i1]); a1.x += w2*v.x; a1.y += w2*v.y;
        v = bfp2f(r3[i1]); a1.x += w3*v.x; a1.y += w3*v.y;
        if (t3) {
            v = bfp2f(r0[i2]); a2.x += w0*v.x; a2.y += w0*v.y;
            v = bfp2f(r1[i2]); a2.x += w1*v.x; a2.y += w1*v.y;
            v = bfp2f(r2[i2]); a2.x += w2*v.x; a2.y += w2*v.y;
            v = bfp2f(r3[i2]); a2.x += w3*v.x; a2.y += w3*v.y;
        }
    }
    for (; e < end; ++e) {
        const ushort2* r0 = (const ushort2*)(xg + (long)jp[e]*ldx);
        float w0 = nm[e];
        float2 v;
        v = bfp2f(r0[i0]); a0.x += w0*v.x; a0.y += w0*v.y;
        v = bfp2f(r0[i1]); a1.x += w0*v.x; a1.y += w0*v.y;
        if (t3) { v = bfp2f(r0[i2]); a2.x += w0*v.x; a2.y += w0*v.y; }
    }
    // highway: o = sig(gl+b)*relu(acc) + (1-sig)*x1
    const ushort2* glr = (const ushort2*)(gl + (long)w*ldx);
    const float2*  x1r = (const float2*)(x1 + (long)w*ld1);
    const float2*  br  = (const float2*)bias;
    float2* dst = (float2*)(out + (long)w*ldo);
    float2 o0 = {0,0}, o1 = {0,0}, o2 = {0,0};
    {
        float2 gv = bfp2f(glr[i0]); float2 xv = x1r[i0], bv = br[i0];
        float g0 = 1.0f/(1.0f+expf(-(gv.x+bv.x))), g1 = 1.0f/(1.0f+expf(-(gv.y+bv.y)));
        o0.x = g0*fmaxf(a0.x,0.0f) + (1.0f-g0)*xv.x;
        o0.y = g1*fmaxf(a0.y,0.0f) + (1.0f-g1)*xv.y;
        dst[i0] = o0;
    }
    {
        float2 gv = bfp2f(glr[i1]); float2 xv = x1r[i1], bv = br[i1];
        float g0 = 1.0f/(1.0f+expf(-(gv.x+bv.x))), g1 = 1.0f/(1.0f+expf(-(gv.y+bv.y)));
        o1.x = g0*fmaxf(a1.x,0.0f) + (1.0f-g0)*xv.x;
        o1.y = g1*fmaxf(a1.y,0.0f) + (1.0f-g1)*xv.y;
        dst[i1] = o1;
    }
    if (t3) {
        float2 gv = bfp2f(glr[i2]); float2 xv = x1r[i2], bv = br[i2];
        float g0 = 1.0f/(1.0f+expf(-(gv.x+bv.x))), g1 = 1.0f/(1.0f+expf(-(gv.y+bv.y)));
        o2.x = g0*fmaxf(a2.x,0.0f) + (1.0f-g0)*xv.x;
        o2.y = g1*fmaxf(a2.y,0.0f) + (1.0f-g1)*xv.y;
        dst[i2] = o2;
    }
    if (hi) {   // fragment-pack o as bf16 hi/lo for the next GEMM's A
        auto pack2 = [&](int k, float2 o) {
            unsigned short hx = f2bf_rne(o.x) , hy = f2bf_rne(o.y);
            // hi must be truncation for exact residual; use trunc hi + rne lo
            unsigned ux = __float_as_uint(o.x), uy = __float_as_uint(o.y);
            hx = (unsigned short)(ux >> 16); hy = (unsigned short)(uy >> 16);
            unsigned short lx = f2bf_rne(o.x - bf2f(hx)), ly = f2bf_rne(o.y - bf2f(hy));
            long off = fragoff(w, k, npk);
            ushort2 hv = {hx, hy}, lv = {lx, ly};
            *(ushort2*)(hi + off) = hv;
            *(ushort2*)(lo + off) = lv;
        };
        pack2(2*lane, o0);
        pack2(128 + 2*lane, o1);
        if (t3) pack2(256 + 2*lane, o2);
        else if (lane < 24) {
            long off = fragoff(w, 256 + 2*lane, npk);
            ushort2 z = {0,0};
            *(ushort2*)(hi + off) = z;
            *(ushort2*)(lo + off) = z;
        }
    }
    if (xbf) {  // row-major bf16 copy (stride 304 shorts) for GAT gather
        ushort2* xw = (ushort2*)(xbf + (long)w*304);
        ushort2 t;
        t.x = f2bf_rne(o0.x); t.y = f2bf_rne(o0.y); xw[i0] = t;
        t.x = f2bf_rne(o1.x); t.y = f2bf_rne(o1.y); xw[i1] = t;
        if (t3) { t.x = f2bf_rne(o2.x); t.y = f2bf_rne(o2.y); xw[i2] = t; }
    }
    if (sa) {   // GAT score dots: sa[w] = o·ai, sb[w] = o·aj
        const float2* ai2 = (const float2*)ai;
        const float2* aj2 = (const float2*)aj;
        float2 A0 = ai2[i0], A1 = ai2[i1], J0 = aj2[i0], J1 = aj2[i1];
        float sva = o0.x*A0.x + o0.y*A0.y + o1.x*A1.x + o1.y*A1.y;
        float svb = o0.x*J0.x + o0.y*J0.y + o1.x*J1.x + o1.y*J1.y;
        if (t3) {
            float2 A2 = ai2[i2], J2 = aj2[i2];
            sva += o2.x*A2.x + o2.y*A2.y;
            svb += o2.x*J2.x + o2.y*J2.y;
        }
        #pragma unroll
        for (int o = 32; o > 0; o >>= 1) {
            sva += __shfl_down(sva, o);
            svb += __shfl_down(svb, o);
        }
        if (lane == 0) { sa[w] = sva; sb[w] = svb; }
    }
}

// =========================================================================
// k_gat300: fused edge score + segment softmax + weighted gather (bf16 x)
// + relu -> out cols 300..599, PLUS r2e score dots:
//   sh[w] = x6[w]·ah, st[w] = x6[w]·at  where x6 = [x(0..299), gat(300..599)]
// =========================================================================
__global__ void k_gat300(const unsigned short* __restrict__ xbf,
                         const float* __restrict__ sA, const float* __restrict__ sB,
                         const float* __restrict__ rsc,
                         const int* __restrict__ jp, const int* __restrict__ relp,
                         const int* __restrict__ rowptr, const int* __restrict__ cnt,
                         float* __restrict__ out, long ldo,
                         const float* __restrict__ ah, const float* __restrict__ at,
                         float* __restrict__ sh, float* __restrict__ st,
                         int n)
{
    int w = (blockIdx.x*blockDim.x + threadIdx.x) >> 6;
    int lane = threadIdx.x & 63;
    if (w >= n) return;
    int beg = rowptr[w], c = cnt[w];
    const int i0 = lane, i1 = lane + 64, i2 = lane + 128;
    const bool t3 = (lane < 22);
    float2 a0 = {0,0}, a1 = {0,0}, a2 = {0,0};
    if (c > 0) {
        float base = sA[w];
        int   jc = 0;
        float sval = -3.4e38f;
        if (lane < c) {
            jc = jp[beg + lane];
            sval = leaky(base + sB[jc] + rsc[relp[beg + lane]]);
        }
        float mx = sval;
        for (int t = 64 + lane; t < c; t += 64)
            mx = fmaxf(mx, leaky(base + sB[jp[beg+t]] + rsc[relp[beg+t]]));
        #pragma unroll
        for (int o = 32; o > 0; o >>= 1) mx = fmaxf(mx, __shfl_xor(mx, o));
        float pexp = (lane < c) ? expf(sval - mx) : 0.0f;
        float ss = pexp;
        for (int t = 64 + lane; t < c; t += 64)
            ss += expf(leaky(base + sB[jp[beg+t]] + rsc[relp[beg+t]]) - mx);
        #pragma unroll
        for (int o = 32; o > 0; o >>= 1) ss += __shfl_xor(ss, o);
        float inv = 1.0f / (ss + 1e-16f);
        int q = 0;
        int cc = (c < 64) ? c : 64;
        for (; q + 4 <= cc; q += 4) {
            float al0 = __shfl(pexp, q)   * inv;
            float al1 = __shfl(pexp, q+1) * inv;
            float al2 = __shfl(pexp, q+2) * inv;
            float al3 = __shfl(pexp, q+3) * inv;
            long  j0 = __shfl(jc, q), j1 = __shfl(jc, q+1);
            long  j2 = __shfl(jc, q+2), j3 = __shfl(jc, q+3);
            const ushort2* r0 = (const ushort2*)(xbf + j0*304);
            const ushort2* r1 = (const ushort2*)(xbf + j1*304);
            const ushort2* r2 = (const ushort2*)(xbf + j2*304);
            const ushort2* r3 = (const ushort2*)(xbf + j3*304);
            float2 v;
            v = bfp2f(r0[i0]); a0.x += al0*v.x; a0.y += al0*v.y;
            v = bfp2f(r1[i0]); a0.x += al1*v.x; a0.y += al1*v.y;
            v = bfp2f(r2[i0]); a0.x += al2*v.x; a0.y += al2*v.y;
            v = bfp2f(r3[i0]); a0.x += al3*v.x; a0.y += al3*v.y;
            v = bfp2f(r0[i1]); a1.x += al0*v.x; a1.y += al0*v.y;
            v = bfp2f(r1[i1]); a1.x += al1*v.x; a1.y += al1*v.y;
            v = bfp2f(r2[i1]); a1.x += al2*v.x; a1.y += al2*v.y;
            v = bfp2f(r3[i1]); a1.x += al3*v.x; a1.y += al3*v.y;
            if (t3) {
                v = bfp2f(r0[i2]); a2.x += al0*v.x; a2.y += al0*v.y;
                v = bfp2f(r1[i2]); a2.x += al1*v.x; a2.y += al1*v.y;
                v = bfp2f(r2[i2]); a2.x += al2*v.x; a2.y += al2*v.y;
                v = bfp2f(r3[i2]); a2.x += al3*v.x; a2.y += al3*v.y;
            }
        }
        for (; q < c; ++q) {
            float al; long j0;
            if (q < 64) { al = __shfl(pexp, q) * inv; j0 = __shfl(jc, q); }
            else {
                j0 = jp[beg + q];
                al = expf(leaky(base + sB[(int)j0] + rsc[relp[beg+q]]) - mx) * inv;
            }
            const ushort2* r0 = (const ushort2*)(xbf + j0*304);
            float2 v;
            v = bfp2f(r0[i0]); a0.x += al*v.x; a0.y += al*v.y;
            v = bfp2f(r0[i1]); a1.x += al*v.x; a1.y += al*v.y;
            if (t3) { v = bfp2f(r0[i2]); a2.x += al*v.x; a2.y += al*v.y; }
        }
    }
    // relu
    a0.x = fmaxf(a0.x, 0.0f); a0.y = fmaxf(a0.y, 0.0f);
    a1.x = fmaxf(a1.x, 0.0f); a1.y = fmaxf(a1.y, 0.0f);
    a2.x = fmaxf(a2.x, 0.0f); a2.y = fmaxf(a2.y, 0.0f);
    float2* dst = (float2*)(out + (long)w*ldo);
    dst[i0] = a0; dst[i1] = a1;
    if (t3) dst[i2] = a2;
    // ===== r2e score dots over x6 = [x(0..299) from xbf row w, gat(a*)] =====
    {
        const ushort2* xw = (const ushort2*)(xbf + (long)w*304);
        const float2* ahL = (const float2*)ah;            // cols 0..299
        const float2* atL = (const float2*)at;
        const float2* ahH = (const float2*)(ah + 300);    // cols 300..599
        const float2* atH = (const float2*)(at + 300);
        float2 x0 = bfp2f(xw[i0]), x1v = bfp2f(xw[i1]);
        float svh = x0.x*ahL[i0].x + x0.y*ahL[i0].y + x1v.x*ahL[i1].x + x1v.y*ahL[i1].y
                  + a0.x*ahH[i0].x + a0.y*ahH[i0].y + a1.x*ahH[i1].x + a1.y*ahH[i1].y;
        float svt = x0.x*atL[i0].x + x0.y*atL[i0].y + x1v.x*atL[i1].x + x1v.y*atL[i1].y
                  + a0.x*atH[i0].x + a0.y*atH[i0].y + a1.x*atH[i1].x + a1.y*atH[i1].y;
        if (t3) {
            float2 x2v = bfp2f(xw[i2]);
            svh += x2v.x*ahL[i2].x + x2v.y*ahL[i2].y + a2.x*ahH[i2].x + a2.y*ahH[i2].y;
            svt += x2v.x*atL[i2].x + x2v.y*atL[i2].y + a2.x*atH[i2].x + a2.y*atH[i2].y;
        }
        #pragma unroll
        for (int o = 32; o > 0; o >>= 1) {
            svh += __shfl_down(svh, o);
            svt += __shfl_down(svt, o);
        }
        if (lane == 0) { sh[w] = svh; st[w] = svt; }
    }
}

// r2e: fused score = leaky(snode[w] + srel[relp]) + softmax + gather of xr (F=100)
__global__ void k_gather_rel100(const float* __restrict__ xr,
                                const float* __restrict__ snode,
                                const float* __restrict__ srel,
                                const int* __restrict__ relp,
                                const int* __restrict__ rowptr, const int* __restrict__ cnt,
                                float* __restrict__ out, long ldo, int n)
{
    int w = (blockIdx.x*blockDim.x + threadIdx.x) >> 6;
    int lane = threadIdx.x & 63;
    if (w >= n) return;
    int beg = rowptr[w], c = cnt[w];
    const bool t0 = (lane < 50);
    float2 a0 = {0,0};
    if (c > 0) {
        float base = snode[w];
        int   rc = 0;
        float sval = -3.4e38f;
        if (lane < c) {
            rc = relp[beg + lane];
            sval = leaky(base + srel[rc]);
        }
        float mx = sval;
        for (int t = 64 + lane; t < c; t += 64)
            mx = fmaxf(mx, leaky(base + srel[relp[beg+t]]));
        #pragma unroll
        for (int o = 32; o > 0; o >>= 1) mx = fmaxf(mx, __shfl_xor(mx, o));
        float pexp = (lane < c) ? expf(sval - mx) : 0.0f;
        float ss = pexp;
        for (int t = 64 + lane; t < c; t += 64)
            ss += expf(leaky(base + srel[relp[beg+t]]) - mx);
        #pragma unroll
        for (int o = 32; o > 0; o >>= 1) ss += __shfl_xor(ss, o);
        float inv = 1.0f / (ss + 1e-16f);
        int q = 0;
        int cc = (c < 64) ? c : 64;
        for (; q + 4 <= cc; q += 4) {
            float al0 = __shfl(pexp, q)   * inv;
            float al1 = __shfl(pexp, q+1) * inv;
            float al2 = __shfl(pexp, q+2) * inv;
            float al3 = __shfl(pexp, q+3) * inv;
            long r0i = __shfl(rc, q), r1i = __shfl(rc, q+1);
            long r2i = __shfl(rc, q+2), r3i = __shfl(rc, q+3);
            if (t0) {
                float2 v;
                v = ((const float2*)(xr + r0i*100))[lane]; a0.x += al0*v.x; a0.y += al0*v.y;
                v = ((const float2*)(xr + r1i*100))[lane]; a0.x += al1*v.x; a0.y += al1*v.y;
                v = ((const float2*)(xr + r2i*100))[lane]; a0.x += al2*v.x; a0.y += al2*v.y;
                v = ((const float2*)(xr + r3i*100))[lane]; a0.x += al3*v.x; a0.y += al3*v.y;
            }
        }
        for (; q < c; ++q) {
            float al; long r0i;
            if (q < 64) { al = __shfl(pexp, q) * inv; r0i = __shfl(rc, q); }
            else {
                r0i = relp[beg + q];
                al = expf(leaky(base + srel[(int)r0i]) - mx) * inv;
            }
            if (t0) {
                float2 v = ((const float2*)(xr + r0i*100))[lane];
                a0.x += al*v.x; a0.y += al*v.y;
            }
        }
    }
    if (t0) ((float2*)(out + (long)w*ldo))[lane] = a0;
}

// ---------- highway combine (small R x RH path) ----------
__global__ void k_highway(const float* __restrict__ x1, long ld1,
                          const float* __restrict__ gl, long ldg,
                          const float* __restrict__ x2, long ld2,
                          const float* __restrict__ bias,
                          float* __restrict__ out, long ldo,
                          long rows, int F, int relu_x2)
{
    long idx = (long)blockIdx.x*blockDim.x + threadIdx.x;
    if (idx >= rows * (long)F) return;
    long r = idx / F; int c = (int)(idx % F);
    float g = 1.0f / (1.0f + expf(-(gl[r*ldg+c] + bias[c])));
    float v2 = x2[r*ld2+c]; if (relu_x2) v2 = fmaxf(v2, 0.0f);
    float v1 = x1[r*ld1+c];
    out[r*ldo+c] = g*v2 + (1.0f-g)*v1;
}

// ---------- segment softmax building blocks (small l_gat path only) ----------
__global__ void k_segmax(const float* __restrict__ ev, const int* __restrict__ idx,
                         unsigned* __restrict__ m, int E) {
    int e = blockIdx.x*blockDim.x + threadIdx.x;
    if (e < E) atomicMax(&m[idx[e]], f2mono(ev[e]));
}
__global__ void k_segsumexp(const float* __restrict__ ev, const int* __restrict__ idx,
                            const unsigned* __restrict__ m, float* __restrict__ s, int E) {
    int e = blockIdx.x*blockDim.x + threadIdx.x;
    if (e < E) atomicAdd(&s[idx[e]], expf(ev[e] - mono2f(m[idx[e]])));
}
__global__ void k_lgat_vsum(const float* __restrict__ val,
                            const int* __restrict__ jj, const int* __restrict__ ii,
                            const unsigned* __restrict__ mi, const float* __restrict__ si,
                            const unsigned* __restrict__ mj, const float* __restrict__ sj,
                            float* __restrict__ vsum, int E)
{
    int e = blockIdx.x*blockDim.x + threadIdx.x;
    if (e >= E) return;
    float v = val[e];
    int i = ii[e], j = jj[e];
    float pi = expf(v - mono2f(mi[i])) / (si[i] + 1e-16f);
    float pj = expf(v - mono2f(mj[j])) / (sj[j] + 1e-16f);
    vsum[e] = pi + pj;
}
__global__ void k_edge_agg(const float* __restrict__ ev,
                           const unsigned* __restrict__ m, const float* __restrict__ s,
                           const int* __restrict__ ka, const int* __restrict__ ko,
                           const int* __restrict__ ks,
                           const float* __restrict__ x, long ldx,
                           float* __restrict__ out, long ldo,
                           int E, int F)
{
    int w = (blockIdx.x*blockDim.x + threadIdx.x) >> 6;
    int lane = threadIdx.x & 63;
    if (w >= E) return;
    int a = ka[w];
    float alpha = expf(ev[w] - mono2f(m[a])) / (s[a] + 1e-16f);
    const float4* src = (const float4*)(x + (long)ks[w]*ldx);
    float* dst = out + (long)ko[w]*ldo;
    int nf4 = F >> 2;
    for (int f = lane; f < nf4; f += WAVE) {
        float4 v = src[f];
        atomicAdd(&dst[f*4+0], alpha*v.x);
        atomicAdd(&dst[f*4+1], alpha*v.y);
        atomicAdd(&dst[f*4+2], alpha*v.z);
        atomicAdd(&dst[f*4+3], alpha*v.w);
    }
}
__global__ void k_relu2d(float* __restrict__ p, long rows, int cols, long ld) {
    long idx = (long)blockIdx.x*blockDim.x + threadIdx.x;
    if (idx >= rows*(long)cols) return;
    long r = idx / cols; int c = (int)(idx % cols);
    float v = p[r*ld+c];
    p[r*ld+c] = fmaxf(v, 0.0f);
}

// ---------- row dots (small path: srel) ----------
__global__ void k_rowdot2(const float* __restrict__ x, long ldx, int rows, int K,
                          const float* __restrict__ a, const float* __restrict__ b,
                          float* __restrict__ oa, float* __restrict__ ob)
{
    int w = (blockIdx.x*blockDim.x + threadIdx.x) >> 6;
    int lane = threadIdx.x & 63;
    if (w >= rows) return;
    const float* xr = x + (long)w*ldx;
    float sa = 0.0f, sb = 0.0f;
    for (int k = lane; k < K; k += WAVE) {
        float v = xr[k];
        sa += v * a[k];
        if (b) sb += v * b[k];
    }
    #pragma unroll
    for (int off = 32; off > 0; off >>= 1) {
        sa += __shfl_down(sa, off);
        if (b) sb += __shfl_down(sb, off);
    }
    if (lane == 0) { oa[w] = sa; if (ob) ob[w] = sb; }
}

// ---------- relscore[r] = merge[r]·ar[0:RH] + tri[r]·ar[RH:2RH] ----------
__global__ void k_relscore(const float* __restrict__ mg, const float* __restrict__ tr,
                           const float* __restrict__ ar, float* __restrict__ out, int R, int RH)
{
    int w = (blockIdx.x*blockDim.x + threadIdx.x) >> 6;
    int lane = threadIdx.x & 63;
    if (w >= R) return;
    float s = 0.0f;
    for (int k = lane; k < RH; k += WAVE)
        s += mg[(long)w*RH+k]*ar[k] + tr[(long)w*RH+k]*ar[RH+k];
    #pragma unroll
    for (int off = 32; off > 0; off >>= 1) s += __shfl_down(s, off);
    if (lane == 0) out[w] = s;
}

extern "C" void kernel_launch(void* const* d_in, const int* in_sizes, int n_in,
                              void* d_out, int out_size, void* d_ws, size_t ws_size,
                              hipStream_t stream)
{
    const float* x_e   = (const float*)d_in[0];
    const float* mval  = (const float*)d_in[1];
    const float* tval  = (const float*)d_in[2];
    const float* g1w   = (const float*)d_in[3];
    const float* h1w   = (const float*)d_in[4];
    const float* h1b   = (const float*)d_in[5];
    const float* g2w   = (const float*)d_in[6];
    const float* h2w   = (const float*)d_in[7];
    const float* h2b   = (const float*)d_in[8];
    const float* remb1 = (const float*)d_in[9];
    const float* remb2 = (const float*)d_in[10];
    const float* hrw   = (const float*)d_in[11];
    const float* hrb   = (const float*)d_in[12];
    const float* gat_ai= (const float*)d_in[13];
    const float* gat_aj= (const float*)d_in[14];
    const float* gat_ar= (const float*)d_in[15];
    const float* g2e_ah= (const float*)d_in[16];
    const float* g2e_at= (const float*)d_in[17];
    const float* g2e_ar= (const float*)d_in[18];
    const int* edge_index     = (const int*)d_in[19];
    const int* rel            = (const int*)d_in[20];
    const int* edge_index_all = (const int*)d_in[21];
    const int* rel_all        = (const int*)d_in[22];
    const int* lg_merge       = (const int*)d_in[23];
    const int* lg_tri         = (const int*)d_in[24];

    const int F    = 300;
    const int RH   = 100;
    const int Kp   = 304;                  // padded K
    const int npk  = Kp / 16;              // 19 k-steps
    const int N    = in_sizes[0] / F;      // 100000 (multiple of 32)
    const int E    = in_sizes[20];         // 400000
    const int EA   = in_sizes[22];         // 800000
    const int LGE  = in_sizes[1];          // 60000
    const int R    = in_sizes[9] / RH;     // 2000
    const long OUTC = 800;
    const int Mpad = CDIV(N, 128) * 128;   // 100096
    const int NB   = 640;                  // fused B rows: W_g @0..299, W_h @320..619
    const long LDC = 640;                  // Ascr stride (shorts)

    const int* jA = edge_index_all;
    const int* iA = edge_index_all + EA;
    const int* hE = edge_index;
    const int* tE = edge_index + E;
    const int* jM = lg_merge;  const int* iM = lg_merge + LGE;
    const int* jT = lg_tri;    const int* iT = lg_tri  + LGE;

    float* ws = (float*)d_ws;
    size_t off = 0;
    auto alloc = [&](size_t n) { float* p = ws + off; off += (n + 3) & ~(size_t)3; return p; };
    unsigned short* Ascr = (unsigned short*)alloc((size_t)N*NB/2);        // GEMM out bf16 [N,640]
    unsigned short* Axh = (unsigned short*)alloc((size_t)Mpad*Kp/2);      // A packed hi
    unsigned short* Axl = (unsigned short*)alloc((size_t)Mpad*Kp/2);      // A packed lo
    unsigned short* xbf = (unsigned short*)alloc((size_t)N*304/2);        // row-major bf16 x
    unsigned short* Wh[2]; unsigned short* Wl[2];
    for (int i = 0; i < 2; ++i) {
        Wh[i] = (unsigned short*)alloc((size_t)NB*Kp/2);
        Wl[i] = (unsigned short*)alloc((size_t)NB*Kp/2);
    }
    float*    dinv = alloc(N);
    float*    sA_  = alloc(N);
    float*    sB_  = alloc(N);
    float*    sH_  = alloc(N);
    float*    sT_  = alloc(N);
    float*    mrg  = alloc((size_t)R*RH);
    float*    tri  = alloc((size_t)R*RH);
    float*    xr   = alloc((size_t)R*RH);
    float*    xrg  = alloc((size_t)R*RH);
    unsigned* lmi  = (unsigned*)alloc(R);  float* lsi = alloc(R);
    unsigned* lmj  = (unsigned*)alloc(R);  float* lsj = alloc(R);
    unsigned* lm2  = (unsigned*)alloc(R);  float* ls2 = alloc(R);
    float*    vsum = alloc(LGE);
    float*    rsc  = alloc(R);
    float*    srel = alloc(R);
    int*   bsum    = (int*)alloc(1024);
    int*   cursor  = (int*)alloc(N);
    int*   rowptrA = (int*)alloc(N); int* cntA = (int*)alloc(N); int* permA = (int*)alloc(EA);
    int*   rowptrH = (int*)alloc(N); int* cntH = (int*)alloc(N); int* permH = (int*)alloc(E);
    int*   rowptrT = (int*)alloc(N); int* cntT = (int*)alloc(N); int* permT = (int*)alloc(E);
    int*   jpA     = (int*)alloc(EA);
    float* nmA     = alloc(EA);
    int*   relpA   = (int*)alloc(EA);
    int*   relpH   = (int*)alloc(E);
    int*   relpT   = (int*)alloc(E);

    float* out = (float*)d_out;              // [N, 800]

    const int  nb = CDIV(N, 256);
    dim3 gemmGrid(5, CDIV(N, 128));          // 5 col-blocks x 782 row-blocks
    const int gatherGrid = CDIV(N, 4);
    const int cvtBigGrid = CDIV((long)N * (Kp/4), 256);
    const int cvtWGrid   = CDIV(300 * (Kp/4), 256);

    auto build_csr = [&](const int* key, int E_, int* rowptr, int* cnt, int* perm) {
        hipMemsetAsync(cnt, 0, (size_t)N*4, stream);
        k_hist<<<CDIV(E_,256),256,0,stream>>>(key, cnt, E_);
        k_scan1<<<nb,256,0,stream>>>(cnt, rowptr, bsum, N);
        k_scan2<<<1,1024,0,stream>>>(bsum, nb);
        k_scan3<<<nb,256,0,stream>>>(rowptr, bsum, N);
        hipMemsetAsync(cursor, 0, (size_t)N*4, stream);
        k_fill<<<CDIV(E_,256),256,0,stream>>>(key, rowptr, cursor, perm, E_);
    };

    // ===== zero pads, then fragment-pack converts (fused W: g @0, h @320) =====
    for (int i = 0; i < 2; ++i) {
        hipMemsetAsync(Wh[i], 0, (size_t)NB*Kp*2, stream);
        hipMemsetAsync(Wl[i], 0, (size_t)NB*Kp*2, stream);
    }
    hipMemsetAsync(Axh + (size_t)N*Kp, 0, (size_t)(Mpad-N)*Kp*2, stream);
    hipMemsetAsync(Axl + (size_t)N*Kp, 0, (size_t)(Mpad-N)*Kp*2, stream);
    k_cvt_pack<<<cvtWGrid,256,0,stream>>>(g1w, 300, 300, 300, npk, 0,   Wh[0], Wl[0]);
    k_cvt_pack<<<cvtWGrid,256,0,stream>>>(h1w, 300, 300, 300, npk, 320, Wh[0], Wl[0]);
    k_cvt_pack<<<cvtWGrid,256,0,stream>>>(g2w, 300, 300, 300, npk, 0,   Wh[1], Wl[1]);
    k_cvt_pack<<<cvtWGrid,256,0,stream>>>(h2w, 300, 300, 300, npk, 320, Wh[1], Wl[1]);
    k_cvt_pack<<<cvtBigGrid,256,0,stream>>>(x_e, 300, N, 300, npk, 0, Axh, Axl);

    // ===== CSRs + pre-permutes =====
    build_csr(iA, EA, rowptrA, cntA, permA);
    build_csr(hE, E,  rowptrH, cntH, permH);
    build_csr(tE, E,  rowptrT, cntT, permT);
    k_dinv_cnt<<<CDIV(N,256),256,0,stream>>>(cntA, dinv, N);
    k_prep_gcn<<<CDIV(EA,256),256,0,stream>>>(permA, jA, iA, dinv, jpA, nmA, EA);
    k_permute_mod<<<CDIV(EA,256),256,0,stream>>>(rel_all, permA, relpA, EA, R);
    k_permute_i32<<<CDIV(E,256),256,0,stream>>>(rel, permH, relpH, E);
    k_permute_i32<<<CDIV(E,256),256,0,stream>>>(rel, permT, relpT, E);

    // ===== GCN layer 1: fused double-GEMM (bf16 out) + gather/highway/pack =====
    k_gemm_frag<<<gemmGrid,256,0,stream>>>(Axh, Axl, Wh[0], Wl[0], Ascr, LDC, N, 620, npk);
    k_gather_hw<<<gatherGrid,256,0,stream>>>(Ascr, LDC, Ascr+320, x_e, 300, h1b,
                                             jpA, nmA, rowptrA, cntA,
                                             out, OUTC, Axh, Axl,
                                             (unsigned short*)nullptr,
                                             (const float*)nullptr, (const float*)nullptr,
                                             (float*)nullptr, (float*)nullptr, npk, N);

    // ===== GCN layer 2: + xbf emit + GAT score dots =====
    k_gemm_frag<<<gemmGrid,256,0,stream>>>(Axh, Axl, Wh[1], Wl[1], Ascr, LDC, N, 620, npk);
    k_gather_hw<<<gatherGrid,256,0,stream>>>(Ascr, LDC, Ascr+320, out, OUTC, h2b,
                                             jpA, nmA, rowptrA, cntA,
                                             out, OUTC,
                                             (unsigned short*)nullptr, (unsigned short*)nullptr,
                                             xbf, gat_ai, gat_aj, sA_, sB_, npk, N);

    // ===== l_gat on the two line graphs (small; atomic path) =====
    auto lgat = [&](const float* xrel, const int* jjE, const int* iiE, const float* val, float* obuf) {
        hipMemsetAsync(lmi, 0, R*4, stream); hipMemsetAsync(lsi, 0, R*4, stream);
        hipMemsetAsync(lmj, 0, R*4, stream); hipMemsetAsync(lsj, 0, R*4, stream);
        hipMemsetAsync(lm2, 0, R*4, stream); hipMemsetAsync(ls2, 0, R*4, stream);
        hipMemsetAsync(obuf, 0, (size_t)R*RH*4, stream);
        k_segmax   <<<CDIV(LGE,256),256,0,stream>>>(val, iiE, lmi, LGE);
        k_segmax   <<<CDIV(LGE,256),256,0,stream>>>(val, jjE, lmj, LGE);
        k_segsumexp<<<CDIV(LGE,256),256,0,stream>>>(val, iiE, lmi, lsi, LGE);
        k_segsumexp<<<CDIV(LGE,256),256,0,stream>>>(val, jjE, lmj, lsj, LGE);
        k_lgat_vsum<<<CDIV(LGE,256),256,0,stream>>>(val, jjE, iiE, lmi, lsi, lmj, lsj, vsum, LGE);
        k_segmax   <<<CDIV(LGE,256),256,0,stream>>>(vsum, jjE, lm2, LGE);
        k_segsumexp<<<CDIV(LGE,256),256,0,stream>>>(vsum, jjE, lm2, ls2, LGE);
        k_edge_agg <<<(int)CDIV((long)LGE*64,256),256,0,stream>>>(vsum, lm2, ls2, jjE, iiE, jjE,
                                                                  xrel, RH, obuf, RH, LGE, RH);
        k_relu2d   <<<CDIV((long)R*RH,256),256,0,stream>>>(obuf, R, RH, RH);
    };
    lgat(remb1, jM, iM, mval, mrg);
    lgat(remb2, jT, iT, tval, tri);

    // ===== x_r = highway(mrg, tri, hrw, hrb) =====
    dim3 gridR(CDIV(RH,GBN), CDIV(R,GBM));
    k_gemm<<<gridR,256,0,stream>>>(mrg, RH, hrw, RH, xrg, RH, R, RH, RH);
    k_highway<<<CDIV((long)R*RH,256),256,0,stream>>>(mrg, RH, xrg, RH, tri, RH, hrb, xr, RH, R, RH, 0);

    // relscore[r] = rel_cat[r]·gat_ar
    k_relscore<<<CDIV((long)R*64,256),256,0,stream>>>(mrg, tri, gat_ar, rsc, R, RH);

    // ===== GAT -> out cols 300..599 + r2e score dots (fully fused) =====
    k_gat300<<<gatherGrid,256,0,stream>>>(xbf, sA_, sB_, rsc, jpA, relpA,
                                          rowptrA, cntA, out+300, OUTC,
                                          g2e_ah, g2e_at, sH_, sT_, N);

    // ===== gat_r_to_e over edge_index -> out cols 600..799 =====
    k_rowdot2<<<CDIV((long)R*64,256),256,0,stream>>>(xr, RH, R, RH, g2e_ar, (const float*)nullptr,
                                                     srel, (float*)nullptr);
    k_gather_rel100<<<gatherGrid,256,0,stream>>>(xr, sH_, srel, relpH, rowptrH, cntH,
                                                 out+600, OUTC, N);
    k_gather_rel100<<<gatherGrid,256,0,stream>>>(xr, sT_, srel, relpT, rowptrT, cntT,
                                                 out+700, OUTC, N);
}